// Round 4
// baseline (1181.355 us; speedup 1.0000x reference)
//
#include <hip/hip_runtime.h>
#include <math.h>

#define HEADS 8
#define POINTS 4
#define BSZ 2
#define CDIM 256
#define HH 200
#define WW 200
#define LQ (HH * WW)          // 40000
#define MTOT (BSZ * LQ)       // 80000 rows, batch folded into M
#define NLAYERS 3

typedef __attribute__((ext_vector_type(8))) short shortx8;   // 8 bf16 = 4 VGPR
typedef __attribute__((ext_vector_type(4))) float floatx4;

__device__ __forceinline__ ushort f2b(float f) {
    union { float f; unsigned u; } v; v.f = f;
    unsigned r = v.u + 0x7fffu + ((v.u >> 16) & 1u);   // RNE
    return (ushort)(r >> 16);
}
__device__ __forceinline__ float b2f(ushort b) {
    union { unsigned u; float f; } v; v.u = ((unsigned)b) << 16;
    return v.f;
}
__device__ __forceinline__ float bitsf(unsigned u) {
    union { unsigned u; float f; } v; v.u = u;
    return v.f;
}
__device__ __forceinline__ uint packbf(float lo, float hi) {
    return (uint)f2b(lo) | ((uint)f2b(hi) << 16);
}

// Within-64-quadrant channel permutation: channel c = q*64 + nt*16 + lr is
// STORED at position q*64 + lr*4 + nt. Makes each lane's 4 epilogue values
// contiguous -> float4/ushort4 coalesced stores. Consumers use k-permuted
// weights so GEMM results are unchanged (dot products are order-invariant).
__device__ __forceinline__ int permc(int c) {   // channel -> stored position
    return (c & ~63) | (((c & 15) << 2) | ((c & 63) >> 4));
}
__device__ __forceinline__ int iperm(int p) {   // stored position -> channel
    return (p & ~63) | (((p & 3) << 4) | ((p & 63) >> 2));
}

// ---------------------------------------------------------------------------
// fp32 -> bf16 convert, standard layout (n multiple of 1024)
// ---------------------------------------------------------------------------
__global__ __launch_bounds__(256)
void cvt_kernel(const float* __restrict__ in, ushort* __restrict__ out)
{
    const int i = (blockIdx.x * 256 + threadIdx.x) * 4;
    const float4 v = *(const float4*)(in + i);
    ushort4 o;
    o.x = f2b(v.x); o.y = f2b(v.y); o.z = f2b(v.z); o.w = f2b(v.w);
    *(ushort4*)(out + i) = o;
}

// ---------------------------------------------------------------------------
// fp32 -> bf16 convert with K-PERMUTED columns (weights whose A-operand is a
// perm-layout activation). Rows of length 256. out[n][p] = in[n][iperm(p)].
// ---------------------------------------------------------------------------
__global__ __launch_bounds__(256)
void cvt_perm_kernel(const float* __restrict__ in, ushort* __restrict__ out)
{
    const int idx = (blockIdx.x * 256 + threadIdx.x) * 4;   // output position
    const int rowb = idx & ~255;
    const int p0 = idx & 255;
    ushort4 o;
    o.x = f2b(in[rowb + iperm(p0 + 0)]);
    o.y = f2b(in[rowb + iperm(p0 + 1)]);
    o.z = f2b(in[rowb + iperm(p0 + 2)]);
    o.w = f2b(in[rowb + iperm(p0 + 3)]);
    *(ushort4*)(out + idx) = o;
}

// ---------------------------------------------------------------------------
// Build packed off+aw weight [3][128][256] bf16 (K-PERMUTED: consumed against
// perm-layout q) and bias [3][128] fp32.
// ---------------------------------------------------------------------------
__global__ __launch_bounds__(256)
void build_offaw(const float* __restrict__ offw, const float* __restrict__ offb,
                 const float* __restrict__ aww, const float* __restrict__ awb,
                 ushort* __restrict__ wout, float* __restrict__ bout)
{
    const int blk = blockIdx.x;          // 3*128 blocks
    const int i = blk >> 7;
    const int r = blk & 127;
    const int c = threadIdx.x;
    float v = 0.f;
    if (r < 64)      v = offw[((size_t)i * 64 + r) * CDIM + c];
    else if (r < 96) v = aww[((size_t)i * 32 + (r - 64)) * CDIM + c];
    wout[((size_t)i * 128 + r) * CDIM + permc(c)] = f2b(v);
    if (c == 0) {
        float bb = 0.f;
        if (r < 64)      bb = offb[i * 64 + r];
        else if (r < 96) bb = awb[i * 32 + (r - 64)];
        bout[i * 128 + r] = bb;
    }
}

// ---------------------------------------------------------------------------
// Sine positional encoding -> bf16 [LQ, 256], PERM layout (read by QOUT path)
// ---------------------------------------------------------------------------
__global__ __launch_bounds__(256)
void pos_kernel(ushort* __restrict__ pos)
{
    const int idx = blockIdx.x * 256 + threadIdx.x;
    const int c = idx & 255;
    const int l = idx >> 8;
    const int cc = c & 127;
    const float coord = (c < 128) ? (float)(l / WW + 1) : (float)(l % WW + 1);
    const float expo = (float)(2 * (cc >> 1)) * (1.0f / 128.0f);
    const float t = powf(10000.0f, expo);
    const float ph = coord / t;
    pos[(size_t)l * CDIM + permc(c)] = f2b((cc & 1) ? cosf(ph) : sinf(ph));
}

// ---------------------------------------------------------------------------
// bev [BS, C, HW] fp32 -> [BS*HW, C] bf16 STD layout (32x32 LDS transpose)
// ---------------------------------------------------------------------------
__global__ __launch_bounds__(256)
void bevT_kernel(const float* __restrict__ in, ushort* __restrict__ out)
{
    __shared__ float tile[32][33];
    const int b = blockIdx.z;
    const int l0 = blockIdx.x * 32;
    const int c0 = blockIdx.y * 32;
    const float* ib = in + (size_t)b * CDIM * LQ;
    ushort* ob = out + (size_t)b * LQ * CDIM;
    #pragma unroll
    for (int j = 0; j < 32; j += 8)
        tile[threadIdx.y + j][threadIdx.x] =
            ib[(size_t)(c0 + threadIdx.y + j) * LQ + l0 + threadIdx.x];
    __syncthreads();
    #pragma unroll
    for (int j = 0; j < 32; j += 8)
        ob[(size_t)(l0 + threadIdx.y + j) * CDIM + c0 + threadIdx.x] =
            f2b(tile[threadIdx.x][threadIdx.y + j]);
}

// ---------------------------------------------------------------------------
// Legacy 128x128 MFMA GEMM, reg-staged — kept ONLY for the N=128 offaw GEMM.
// A may be perm-layout iff B is k-permuted to match (order-invariant dot).
// ---------------------------------------------------------------------------
#define LSTR 40   // LDS row stride in shorts (80 B), conflict-light for b128

template<bool RELU, bool F32OUT, bool BF16OUT, bool QOUT>
__global__ __launch_bounds__(256)
void mfma_gemm(const ushort* __restrict__ A, const ushort* __restrict__ B,
               const float* __restrict__ bias,
               float* __restrict__ Cf, ushort* __restrict__ Cb,
               ushort* __restrict__ Cq, const ushort* __restrict__ posb,
               int N, int K)
{
    __shared__ ushort As[128 * LSTR];
    __shared__ ushort Bs[128 * LSTR];
    const int tid = threadIdx.x;
    const int lane = tid & 63;
    const int wave = tid >> 6;
    const int wr = (wave >> 1) * 64;
    const int wc = (wave & 1) * 64;
    const int rowBase = blockIdx.y * 128;
    const int colBase = blockIdx.x * 128;

    floatx4 acc[4][4];
    #pragma unroll
    for (int i = 0; i < 4; i++)
        #pragma unroll
        for (int j = 0; j < 4; j++) {
            floatx4 z = {0.f, 0.f, 0.f, 0.f};
            acc[i][j] = z;
        }

    const int strow = tid >> 2;
    const int stcol = (tid & 3) * 8;
    const int kq = (lane >> 4) * 8;
    const int lr = lane & 15;

    for (int k0 = 0; k0 < K; k0 += 32) {
        #pragma unroll
        for (int j = 0; j < 2; j++) {
            const int r = j * 64 + strow;
            const uint4 av = *(const uint4*)(A + (size_t)(rowBase + r) * K + k0 + stcol);
            const uint4 bv = *(const uint4*)(B + (size_t)(colBase + r) * K + k0 + stcol);
            *(uint4*)(As + r * LSTR + stcol) = av;
            *(uint4*)(Bs + r * LSTR + stcol) = bv;
        }
        __syncthreads();
        shortx8 af[4], bfr[4];
        #pragma unroll
        for (int t = 0; t < 4; t++) {
            af[t]  = *(const shortx8*)(As + (wr + t * 16 + lr) * LSTR + kq);
            bfr[t] = *(const shortx8*)(Bs + (wc + t * 16 + lr) * LSTR + kq);
        }
        #pragma unroll
        for (int mt = 0; mt < 4; mt++)
            #pragma unroll
            for (int nt = 0; nt < 4; nt++)
                acc[mt][nt] = __builtin_amdgcn_mfma_f32_16x16x32_bf16(
                    af[mt], bfr[nt], acc[mt][nt], 0, 0, 0);
        __syncthreads();
    }

    const int colB = colBase + wc + lr;
    const int rowB = rowBase + wr + (lane >> 4) * 4;
    #pragma unroll
    for (int mt = 0; mt < 4; mt++) {
        #pragma unroll
        for (int r = 0; r < 4; r++) {
            const int m = rowB + mt * 16 + r;
            const int pr = (m >= LQ) ? m - LQ : m;
            #pragma unroll
            for (int nt = 0; nt < 4; nt++) {
                const int n = colB + nt * 16;
                float v = acc[mt][nt][r] + bias[n];
                if (RELU) v = fmaxf(v, 0.f);
                if (F32OUT) Cf[(size_t)m * N + n] = v;
                if (BF16OUT) Cb[(size_t)m * N + n] = f2b(v);
                if (QOUT) {
                    const float pv = b2f(posb[(size_t)pr * CDIM + n]);
                    Cq[(size_t)m * N + n] = f2b(v + pv);
                }
            }
        }
    }
}

// ---------------------------------------------------------------------------
// Full-N MFMA GEMM v3: BM=128, BN=256, BK=32, 512 thr = 8 waves (2 row x 4
// col quadrants of 64x64). DOUBLE-BUFFERED LDS, ONE barrier per K-step:
//   barrier -> issue loads(k+1) -> ds_read buf[p] + 16 MFMA -> ds_write buf[p^1]
// Loads for k+1 overlap the MFMA phase of step k; buffer reuse hazards are
// separated by exactly one barrier. 625 blocks; B restaged half as often as
// the BM=64 version; 3 uint4 staged per thread per step.
//
// Epilogue identical in semantics to v2: resid ALWAYS perm-layout float4;
// PERMC => Cb/Cq/pos perm ushort4; LN = fused residual+LayerNorm with
// 16-lane shfl + cross-wave LDS reduce (red aliases As[0]).
// ---------------------------------------------------------------------------
template<bool RELU, bool LN, bool F32OUT, bool BF16OUT, bool QOUT, bool PERMC>
__global__ __launch_bounds__(512, 4)
void gemm_fused(const ushort* __restrict__ A, const ushort* __restrict__ B,
                const float* __restrict__ bias,
                float* __restrict__ resid, ushort* __restrict__ Cb,
                ushort* __restrict__ Cq, const ushort* __restrict__ posb,
                const float* __restrict__ g, const float* __restrict__ beta)
{
    __shared__ ushort As[2][128 * LSTR];   // 2 x 10240 B
    __shared__ ushort Bs[2][256 * LSTR];   // 2 x 20480 B

    const int tid = threadIdx.x;
    const int lane = tid & 63;
    const int wave = tid >> 6;            // 0..7
    const int lr = lane & 15;
    const int hi = lane >> 4;
    const int rowBase = blockIdx.x * 128;
    const int wr = (wave >> 2) * 64;      // 0 / 64
    const int wc = (wave & 3) * 64;       // 0,64,128,192

    floatx4 acc[4][4];
    #pragma unroll
    for (int i = 0; i < 4; i++)
        #pragma unroll
        for (int j = 0; j < 4; j++) {
            floatx4 z = {0.f, 0.f, 0.f, 0.f};
            acc[i][j] = z;
        }

    const int strow = tid >> 2;          // 0..127
    const int stcol = (tid & 3) * 8;     // 0,8,16,24 (shorts)
    const int kq = hi * 8;

    const ushort* ag = A + (size_t)(rowBase + strow) * CDIM + stcol;
    const ushort* bg = B + (size_t)strow * CDIM + stcol;

    // prologue: stage tile 0 into buf 0
    {
        const uint4 av  = *(const uint4*)(ag);
        const uint4 bv0 = *(const uint4*)(bg);
        const uint4 bv1 = *(const uint4*)(bg + 128 * CDIM);
        *(uint4*)(As[0] + strow * LSTR + stcol) = av;
        *(uint4*)(Bs[0] + strow * LSTR + stcol) = bv0;
        *(uint4*)(Bs[0] + (strow + 128) * LSTR + stcol) = bv1;
    }

    #pragma unroll
    for (int kt = 0; kt < 8; ++kt) {
        const int p = kt & 1;
        __syncthreads();
        uint4 av, bv0, bv1;
        if (kt < 7) {
            const int ko = (kt + 1) * 32;
            av  = *(const uint4*)(ag + ko);
            bv0 = *(const uint4*)(bg + ko);
            bv1 = *(const uint4*)(bg + ko + 128 * CDIM);
        }
        shortx8 af[4], bfr[4];
        #pragma unroll
        for (int t = 0; t < 4; t++) {
            af[t]  = *(const shortx8*)(As[p] + (wr + t * 16 + lr) * LSTR + kq);
            bfr[t] = *(const shortx8*)(Bs[p] + (wc + t * 16 + lr) * LSTR + kq);
        }
        #pragma unroll
        for (int mt = 0; mt < 4; mt++)
            #pragma unroll
            for (int nt = 0; nt < 4; nt++)
                acc[mt][nt] = __builtin_amdgcn_mfma_f32_16x16x32_bf16(
                    af[mt], bfr[nt], acc[mt][nt], 0, 0, 0);
        if (kt < 7) {
            *(uint4*)(As[p ^ 1] + strow * LSTR + stcol) = av;
            *(uint4*)(Bs[p ^ 1] + strow * LSTR + stcol) = bv0;
            *(uint4*)(Bs[p ^ 1] + (strow + 128) * LSTR + stcol) = bv1;
        }
    }
    __syncthreads();   // K-loop LDS use complete (enables red alias)

    // C/D layout: col = lane&15, row = (lane>>4)*4 + reg  [m89/m91 verified]
    float bcol[4];
    #pragma unroll
    for (int nt = 0; nt < 4; nt++) bcol[nt] = bias[wc + nt * 16 + lr];

    if (LN) {
        float2 (*red)[4] = (float2(*)[4])As[0];   // 128 x 4 x 8 B = 4 KB
        // pass 1: x = acc + bias + resid(perm, float4); per-row partial stats
        #pragma unroll
        for (int mt = 0; mt < 4; mt++) {
            #pragma unroll
            for (int r = 0; r < 4; r++) {
                const int mrel = wr + mt * 16 + hi * 4 + r;
                const int m = rowBase + mrel;
                const float4 rv = *(const float4*)(resid + (size_t)m * CDIM + wc + lr * 4);
                float s = 0.f, sq = 0.f;
                #pragma unroll
                for (int nt = 0; nt < 4; nt++) {
                    float x = acc[mt][nt][r] + bcol[nt] + (&rv.x)[nt];
                    acc[mt][nt][r] = x;
                    s += x; sq += x * x;
                }
                #pragma unroll
                for (int o = 8; o >= 1; o >>= 1) {   // reduce over 16-lane group
                    s  += __shfl_xor(s, o, 64);
                    sq += __shfl_xor(sq, o, 64);
                }
                if (lr == 0) { float2 t2; t2.x = s; t2.y = sq; red[mrel][wave & 3] = t2; }
            }
        }
        __syncthreads();
        float gcol[4], btcol[4];
        #pragma unroll
        for (int nt = 0; nt < 4; nt++) {
            gcol[nt]  = g[wc + nt * 16 + lr];
            btcol[nt] = beta[wc + nt * 16 + lr];
        }
        #pragma unroll
        for (int mt = 0; mt < 4; mt++) {
            #pragma unroll
            for (int r = 0; r < 4; r++) {
                const int mrel = wr + mt * 16 + hi * 4 + r;
                const int m = rowBase + mrel;
                const float2 t0 = red[mrel][0], t1 = red[mrel][1];
                const float2 t2 = red[mrel][2], t3 = red[mrel][3];
                const float S  = (t0.x + t1.x) + (t2.x + t3.x);
                const float SQ = (t0.y + t1.y) + (t2.y + t3.y);
                const float mean = S * (1.0f / CDIM);
                const float var = SQ * (1.0f / CDIM) - mean * mean;
                const float rstd = rsqrtf(var + 1e-5f);
                const int pr = (m >= LQ) ? m - LQ : m;
                float4 wv;
                ushort4 ob, qq;
                ushort4 pp;
                if (QOUT) pp = *(const ushort4*)(posb + (size_t)pr * CDIM + wc + lr * 4);
                #pragma unroll
                for (int nt = 0; nt < 4; nt++) {
                    const float y = (acc[mt][nt][r] - mean) * rstd * gcol[nt] + btcol[nt];
                    (&wv.x)[nt] = y;
                    if (BF16OUT) (&ob.x)[nt] = f2b(y);
                    if (QOUT)    (&qq.x)[nt] = f2b(y + b2f((&pp.x)[nt]));
                }
                *(float4*)(resid + (size_t)m * CDIM + wc + lr * 4) = wv;
                if (BF16OUT) *(ushort4*)(Cb + (size_t)m * CDIM + wc + lr * 4) = ob;
                if (QOUT)    *(ushort4*)(Cq + (size_t)m * CDIM + wc + lr * 4) = qq;
            }
        }
    } else {
        #pragma unroll
        for (int mt = 0; mt < 4; mt++) {
            #pragma unroll
            for (int r = 0; r < 4; r++) {
                const int m = rowBase + wr + mt * 16 + hi * 4 + r;
                const int pr = (m >= LQ) ? m - LQ : m;
                float4 wv;
                ushort4 ob, qq, pp;
                if (QOUT && PERMC)
                    pp = *(const ushort4*)(posb + (size_t)pr * CDIM + wc + lr * 4);
                #pragma unroll
                for (int nt = 0; nt < 4; nt++) {
                    float y = acc[mt][nt][r] + bcol[nt];
                    if (RELU) y = fmaxf(y, 0.f);
                    (&wv.x)[nt] = y;
                    if (PERMC) {
                        if (BF16OUT) (&ob.x)[nt] = f2b(y);
                        if (QOUT)    (&qq.x)[nt] = f2b(y + b2f((&pp.x)[nt]));
                    } else {
                        const int col = wc + nt * 16 + lr;
                        if (BF16OUT) Cb[(size_t)m * CDIM + col] = f2b(y);
                        if (QOUT) Cq[(size_t)m * CDIM + col] =
                            f2b(y + b2f(posb[(size_t)pr * CDIM + col]));
                    }
                }
                if (F32OUT) *(float4*)(resid + (size_t)m * CDIM + wc + lr * 4) = wv;
                if (PERMC && BF16OUT)
                    *(ushort4*)(Cb + (size_t)m * CDIM + wc + lr * 4) = ob;
                if (PERMC && QOUT)
                    *(ushort4*)(Cq + (size_t)m * CDIM + wc + lr * 4) = qq;
            }
        }
    }
}

// ---------------------------------------------------------------------------
// Deformable sampling v2: 2 queries per wave (32 lanes each), lane covers
// 8 channels of one head via uint4 gathers. val/attn in STD layout.
// ---------------------------------------------------------------------------
__global__ __launch_bounds__(256)
void sample_kernel(const ushort* __restrict__ val,
                   const float* __restrict__ offaw,
                   ushort* __restrict__ attn)
{
    const int tid = threadIdx.x;
    const int m = blockIdx.x * 8 + (tid >> 5);   // grid.x = MTOT/8
    const int lane = tid & 31;
    const int head = lane >> 2;                  // 4 lanes per head
    const int c = head * 32 + (lane & 3) * 8;    // 8 channels per lane
    const int b = (m >= LQ) ? 1 : 0;
    const int l = m - (b ? LQ : 0);

    const float* row = offaw + (size_t)m * 128;
    const float4 lg  = *(const float4*)(row + 64 + head * 4);
    const float4 o01 = *(const float4*)(row + head * 8);
    const float4 o23 = *(const float4*)(row + head * 8 + 4);

    const float mx = fmaxf(fmaxf(lg.x, lg.y), fmaxf(lg.z, lg.w));
    const float e0 = expf(lg.x - mx), e1 = expf(lg.y - mx);
    const float e2 = expf(lg.z - mx), e3 = expf(lg.w - mx);
    const float inv = 1.0f / (e0 + e1 + e2 + e3);
    const float awv[4] = {e0 * inv, e1 * inv, e2 * inv, e3 * inv};

    const float lx = (float)(l % WW);
    const float ly = (float)(l / WW);
    const float px[4] = {lx + o01.x, lx + o01.z, lx + o23.x, lx + o23.z};
    const float py[4] = {ly + o01.y, ly + o01.w, ly + o23.y, ly + o23.w};

    const ushort* vb = val + (size_t)b * LQ * CDIM;
    uint4 cv[16];
    float cw[16];
    #pragma unroll
    for (int p = 0; p < POINTS; p++) {
        const float x = px[p], y = py[p];
        const float xf = floorf(x), yf = floorf(y);
        const int x0 = (int)xf, y0 = (int)yf;
        const float wx = x - xf, wy = y - yf;
        const int x0c = min(max(x0, 0), WW - 1);
        const int x1c = min(max(x0 + 1, 0), WW - 1);
        const int y0c = min(max(y0, 0), HH - 1);
        const int y1c = min(max(y0 + 1, 0), HH - 1);
        const float vx0 = (x0 >= 0 && x0 < WW) ? 1.f : 0.f;
        const float vx1 = (x0 + 1 >= 0 && x0 + 1 < WW) ? 1.f : 0.f;
        const float vy0 = (y0 >= 0 && y0 < HH) ? 1.f : 0.f;
        const float vy1 = (y0 + 1 >= 0 && y0 + 1 < HH) ? 1.f : 0.f;
        const float a = awv[p];
        cw[p * 4 + 0] = a * (1.f - wx) * (1.f - wy) * vx0 * vy0;
        cw[p * 4 + 1] = a * wx * (1.f - wy) * vx1 * vy0;
        cw[p * 4 + 2] = a * (1.f - wx) * wy * vx0 * vy1;
        cw[p * 4 + 3] = a * wx * wy * vx1 * vy1;
        const int r0 = y0c * WW, r1 = y1c * WW;
        cv[p * 4 + 0] = *(const uint4*)(vb + (((unsigned)(r0 + x0c)) << 8) + c);
        cv[p * 4 + 1] = *(const uint4*)(vb + (((unsigned)(r0 + x1c)) << 8) + c);
        cv[p * 4 + 2] = *(const uint4*)(vb + (((unsigned)(r1 + x0c)) << 8) + c);
        cv[p * 4 + 3] = *(const uint4*)(vb + (((unsigned)(r1 + x1c)) << 8) + c);
    }
    float a0 = 0.f, a1 = 0.f, a2 = 0.f, a3 = 0.f;
    float a4 = 0.f, a5 = 0.f, a6 = 0.f, a7 = 0.f;
    #pragma unroll
    for (int i = 0; i < 16; i++) {
        const float wgt = cw[i];
        a0 = fmaf(wgt, bitsf(cv[i].x << 16), a0);
        a1 = fmaf(wgt, bitsf(cv[i].x & 0xffff0000u), a1);
        a2 = fmaf(wgt, bitsf(cv[i].y << 16), a2);
        a3 = fmaf(wgt, bitsf(cv[i].y & 0xffff0000u), a3);
        a4 = fmaf(wgt, bitsf(cv[i].z << 16), a4);
        a5 = fmaf(wgt, bitsf(cv[i].z & 0xffff0000u), a5);
        a6 = fmaf(wgt, bitsf(cv[i].w << 16), a6);
        a7 = fmaf(wgt, bitsf(cv[i].w & 0xffff0000u), a7);
    }
    uint4 o;
    o.x = packbf(a0, a1); o.y = packbf(a2, a3);
    o.z = packbf(a4, a5); o.w = packbf(a6, a7);
    *(uint4*)(attn + (size_t)m * CDIM + c) = o;
}

// ---------------------------------------------------------------------------
// Final transpose: [b, l, p] fp32 PERM layout -> d_out [b, c, l] (std).
// ---------------------------------------------------------------------------
__global__ __launch_bounds__(256)
void transpose_out(const float* __restrict__ in, float* __restrict__ outp)
{
    __shared__ float tile[32][33];
    const int b = blockIdx.z;
    const int l0 = blockIdx.x * 32;
    const int c0 = blockIdx.y * 32;
    const float* ib = in + (size_t)b * LQ * CDIM;
    float* ob = outp + (size_t)b * CDIM * LQ;
    #pragma unroll
    for (int j = 0; j < 32; j += 8)
        tile[threadIdx.y + j][threadIdx.x] =
            ib[(size_t)(l0 + threadIdx.y + j) * CDIM + c0 + threadIdx.x];
    __syncthreads();
    #pragma unroll
    for (int j = 0; j < 32; j += 8)
        ob[(size_t)iperm(c0 + threadIdx.y + j) * LQ + l0 + threadIdx.x] =
            tile[threadIdx.x][threadIdx.y + j];
}

// ---------------------------------------------------------------------------
extern "C" void kernel_launch(void* const* d_in, const int* in_sizes, int n_in,
                              void* d_out, int out_size, void* d_ws, size_t ws_size,
                              hipStream_t stream)
{
    const float* bev      = (const float*)d_in[0];
    const float* proj_q_w = (const float*)d_in[1];
    const float* proj_q_b = (const float*)d_in[2];
    const float* off_w    = (const float*)d_in[3];
    const float* off_b    = (const float*)d_in[4];
    const float* aw_w     = (const float*)d_in[5];
    const float* aw_b     = (const float*)d_in[6];
    const float* vp_w     = (const float*)d_in[7];
    const float* vp_b     = (const float*)d_in[8];
    const float* op_w     = (const float*)d_in[9];
    const float* op_b     = (const float*)d_in[10];
    const float* ln1_g    = (const float*)d_in[11];
    const float* ln1_b    = (const float*)d_in[12];
    const float* l1_w     = (const float*)d_in[13];
    const float* l1_b     = (const float*)d_in[14];
    const float* l2_w     = (const float*)d_in[15];
    const float* l2_b     = (const float*)d_in[16];
    const float* ln2_g    = (const float*)d_in[17];
    const float* ln2_b    = (const float*)d_in[18];
    float* outp = (float*)d_out;

    // ---- workspace layout ----
    char* w = (char*)d_ws;
    float*  out_f   = (float*)(w);                     // [MTOT,256] fp32 resid (perm)
    float*  offaw_f = (float*)(w + 81920000);          // [MTOT,128] fp32 (std)
    ushort* out_b   = (ushort*)(w + 163840000);        // [MTOT,256] bf16 (perm)
    ushort* q_b     = (ushort*)(w + 204800000);        // [MTOT,256] bf16 (perm q / std attn)
    ushort* val_b   = (ushort*)(w + 245760000);        // [MTOT,256] bf16 (std bevT/value; perm hidden)
    ushort* pos_b   = (ushort*)(w + 286720000);        // [LQ,256] bf16 (perm)
    ushort* w_b     = (ushort*)(w + 307200000);        // packed bf16 weights
    ushort* wproj = w_b;                               // 65536 (std k)
    ushort* wvp   = w_b + 65536;                       // 3*65536 (perm k)
    ushort* wop   = w_b + 65536 + 196608;              // (std k)
    ushort* wl1   = w_b + 65536 + 2 * 196608;          // (perm k)
    ushort* wl2   = w_b + 65536 + 3 * 196608;          // (perm k)
    ushort* wofa  = w_b + 65536 + 4 * 196608;          // 3*128*256 (perm k)
    float*  bofa  = (float*)(w + 307200000 + 2 * (65536 + 4 * 196608 + 98304)); // 3*128

    const dim3 blk(256);
    const dim3 blk512(512);

    // ---- one-time prep (rerun every call: ws is re-poisoned) ----
    cvt_kernel<<<dim3(65536 / 1024), blk, 0, stream>>>(proj_q_w, wproj);
    cvt_perm_kernel<<<dim3(196608 / 1024), blk, 0, stream>>>(vp_w, wvp);
    cvt_kernel<<<dim3(196608 / 1024), blk, 0, stream>>>(op_w, wop);
    cvt_perm_kernel<<<dim3(196608 / 1024), blk, 0, stream>>>(l1_w, wl1);
    cvt_perm_kernel<<<dim3(196608 / 1024), blk, 0, stream>>>(l2_w, wl2);
    build_offaw<<<dim3(3 * 128), blk, 0, stream>>>(off_w, off_b, aw_w, aw_b, wofa, bofa);
    pos_kernel<<<dim3((LQ * CDIM) / 256), blk, 0, stream>>>(pos_b);
    bevT_kernel<<<dim3(LQ / 32, CDIM / 32, BSZ), dim3(32, 8), 0, stream>>>(bev, val_b);

    const dim3 gF(MTOT / 128);                 // 625 blocks, BM=128 full-N tiles
    const dim3 g128(1, MTOT / 128);            // legacy kernel for offaw (N=128)

    // proj: out = bevT @ Wq^T + b ; perm resid + perm out_b + perm q
    gemm_fused<false, false, true, true, true, true><<<gF, blk512, 0, stream>>>(
        val_b, wproj, proj_q_b, out_f, out_b, q_b, pos_b, nullptr, nullptr);

    for (int i = 0; i < NLAYERS; i++) {
        // value = out @ vp^T (std bf16 out for sampler); A perm + k-perm W
        gemm_fused<false, false, false, true, false, false><<<gF, blk512, 0, stream>>>(
            out_b, wvp + (size_t)i * 65536, vp_b + (size_t)i * CDIM,
            nullptr, val_b, nullptr, nullptr, nullptr, nullptr);
        // offaw = q @ [off;aw]^T (fp32 std, N=128); A perm + k-perm W
        mfma_gemm<false, true, false, false><<<g128, blk, 0, stream>>>(
            q_b, wofa + (size_t)i * 32768, bofa + (size_t)i * 128,
            offaw_f, nullptr, nullptr, nullptr, 128, CDIM);
        // sampling -> attn (std bf16, into q_b; q dead now)
        sample_kernel<<<dim3(MTOT / 8), blk, 0, stream>>>(val_b, offaw_f, q_b);
        // out = LN(out + attn @ op^T); A std + std W; perm resid + perm out_b
        gemm_fused<false, true, false, true, false, true><<<gF, blk512, 0, stream>>>(
            q_b, wop + (size_t)i * 65536, op_b + (size_t)i * CDIM,
            out_f, out_b, nullptr, pos_b,
            ln1_g + (size_t)i * CDIM, ln1_b + (size_t)i * CDIM);
        // hidden = relu(out @ l1^T); A perm + k-perm W; perm hidden out
        gemm_fused<true, false, false, true, false, true><<<gF, blk512, 0, stream>>>(
            out_b, wl1 + (size_t)i * 65536, l1_b + (size_t)i * CDIM,
            nullptr, val_b, nullptr, nullptr, nullptr, nullptr);
        // out = LN(out + hidden @ l2^T); A perm + k-perm W; perm resid
        if (i < NLAYERS - 1) {
            gemm_fused<false, true, false, true, true, true><<<gF, blk512, 0, stream>>>(
                val_b, wl2 + (size_t)i * 65536, l2_b + (size_t)i * CDIM,
                out_f, out_b, q_b, pos_b,
                ln2_g + (size_t)i * CDIM, ln2_b + (size_t)i * CDIM);
        } else {
            gemm_fused<false, true, false, false, false, true><<<gF, blk512, 0, stream>>>(
                val_b, wl2 + (size_t)i * 65536, l2_b + (size_t)i * CDIM,
                out_f, nullptr, nullptr, pos_b,
                ln2_g + (size_t)i * CDIM, ln2_b + (size_t)i * CDIM);
        }
    }

    transpose_out<<<dim3(LQ / 32, CDIM / 32, BSZ), dim3(32, 8), 0, stream>>>(out_f, outp);
}

// Round 5
// 1044.084 us; speedup vs baseline: 1.1315x; 1.1315x over previous
//
#include <hip/hip_runtime.h>
#include <math.h>

#define HEADS 8
#define POINTS 4
#define BSZ 2
#define CDIM 256
#define HH 200
#define WW 200
#define LQ (HH * WW)          // 40000
#define MTOT (BSZ * LQ)       // 80000 rows, batch folded into M
#define NLAYERS 3
#define MPAD 40064            // LQ padded to 128 for the posoff GEMM

typedef __attribute__((ext_vector_type(8))) short shortx8;   // 8 bf16 = 4 VGPR
typedef __attribute__((ext_vector_type(4))) float floatx4;

__device__ __forceinline__ ushort f2b(float f) {
    union { float f; unsigned u; } v; v.f = f;
    unsigned r = v.u + 0x7fffu + ((v.u >> 16) & 1u);   // RNE
    return (ushort)(r >> 16);
}
__device__ __forceinline__ float b2f(ushort b) {
    union { unsigned u; float f; } v; v.u = ((unsigned)b) << 16;
    return v.f;
}
__device__ __forceinline__ float bitsf(unsigned u) {
    union { unsigned u; float f; } v; v.u = u;
    return v.f;
}
__device__ __forceinline__ uint packbf(float lo, float hi) {
    return (uint)f2b(lo) | ((uint)f2b(hi) << 16);
}

// Within-64-quadrant channel permutation: channel c = q*64 + nt*16 + lr is
// STORED at position q*64 + lr*4 + nt. Makes each lane's 4 epilogue values
// contiguous -> float4/ushort4 coalesced stores. Consumers use k-permuted
// weights so GEMM results are unchanged (dot products are order-invariant).
__device__ __forceinline__ int permc(int c) {   // channel -> stored position
    return (c & ~63) | (((c & 15) << 2) | ((c & 63) >> 4));
}
__device__ __forceinline__ int iperm(int p) {   // stored position -> channel
    return (p & ~63) | (((p & 3) << 4) | ((p & 63) >> 2));
}

// ---------------------------------------------------------------------------
// fp32 -> bf16 convert, standard layout (n multiple of 1024)
// ---------------------------------------------------------------------------
__global__ __launch_bounds__(256)
void cvt_kernel(const float* __restrict__ in, ushort* __restrict__ out)
{
    const int i = (blockIdx.x * 256 + threadIdx.x) * 4;
    const float4 v = *(const float4*)(in + i);
    ushort4 o;
    o.x = f2b(v.x); o.y = f2b(v.y); o.z = f2b(v.z); o.w = f2b(v.w);
    *(ushort4*)(out + i) = o;
}

// ---------------------------------------------------------------------------
// fp32 -> bf16 convert with K-PERMUTED columns (weights whose A-operand is a
// perm-layout activation). Rows of length 256. out[n][p] = in[n][iperm(p)].
// ---------------------------------------------------------------------------
__global__ __launch_bounds__(256)
void cvt_perm_kernel(const float* __restrict__ in, ushort* __restrict__ out)
{
    const int idx = (blockIdx.x * 256 + threadIdx.x) * 4;   // output position
    const int rowb = idx & ~255;
    const int p0 = idx & 255;
    ushort4 o;
    o.x = f2b(in[rowb + iperm(p0 + 0)]);
    o.y = f2b(in[rowb + iperm(p0 + 1)]);
    o.z = f2b(in[rowb + iperm(p0 + 2)]);
    o.w = f2b(in[rowb + iperm(p0 + 3)]);
    *(ushort4*)(out + idx) = o;
}

// ---------------------------------------------------------------------------
// Build packed off+aw weight [3][128][256] bf16 (K-PERMUTED: consumed against
// perm-layout activations) and bias [3][128] fp32.
// ---------------------------------------------------------------------------
__global__ __launch_bounds__(256)
void build_offaw(const float* __restrict__ offw, const float* __restrict__ offb,
                 const float* __restrict__ aww, const float* __restrict__ awb,
                 ushort* __restrict__ wout, float* __restrict__ bout)
{
    const int blk = blockIdx.x;          // 3*128 blocks
    const int i = blk >> 7;
    const int r = blk & 127;
    const int c = threadIdx.x;
    float v = 0.f;
    if (r < 64)      v = offw[((size_t)i * 64 + r) * CDIM + c];
    else if (r < 96) v = aww[((size_t)i * 32 + (r - 64)) * CDIM + c];
    wout[((size_t)i * 128 + r) * CDIM + permc(c)] = f2b(v);
    if (c == 0) {
        float bb = 0.f;
        if (r < 64)      bb = offb[i * 64 + r];
        else if (r < 96) bb = awb[i * 32 + (r - 64)];
        bout[i * 128 + r] = bb;
    }
}

// ---------------------------------------------------------------------------
// Sine positional encoding -> bf16 [LQ, 256], PERM layout
// ---------------------------------------------------------------------------
__global__ __launch_bounds__(256)
void pos_kernel(ushort* __restrict__ pos)
{
    const int idx = blockIdx.x * 256 + threadIdx.x;
    const int c = idx & 255;
    const int l = idx >> 8;
    const int cc = c & 127;
    const float coord = (c < 128) ? (float)(l / WW + 1) : (float)(l % WW + 1);
    const float expo = (float)(2 * (cc >> 1)) * (1.0f / 128.0f);
    const float t = powf(10000.0f, expo);
    const float ph = coord / t;
    pos[(size_t)l * CDIM + permc(c)] = f2b((cc & 1) ? cosf(ph) : sinf(ph));
}

// ---------------------------------------------------------------------------
// bev [BS, C, HW] fp32 -> [BS*HW, C] bf16 STD layout (32x32 LDS transpose)
// ---------------------------------------------------------------------------
__global__ __launch_bounds__(256)
void bevT_kernel(const float* __restrict__ in, ushort* __restrict__ out)
{
    __shared__ float tile[32][33];
    const int b = blockIdx.z;
    const int l0 = blockIdx.x * 32;
    const int c0 = blockIdx.y * 32;
    const float* ib = in + (size_t)b * CDIM * LQ;
    ushort* ob = out + (size_t)b * LQ * CDIM;
    #pragma unroll
    for (int j = 0; j < 32; j += 8)
        tile[threadIdx.y + j][threadIdx.x] =
            ib[(size_t)(c0 + threadIdx.y + j) * LQ + l0 + threadIdx.x];
    __syncthreads();
    #pragma unroll
    for (int j = 0; j < 32; j += 8)
        ob[(size_t)(l0 + threadIdx.y + j) * CDIM + c0 + threadIdx.x] =
            f2b(tile[threadIdx.x][threadIdx.y + j]);
}

// ---------------------------------------------------------------------------
// Legacy 128x128 MFMA GEMM, reg-staged. Used for the posoff precompute
// (N=384, bf16 out) and the per-layer offaw GEMM (N=128, fp32 out, ROWADD:
// adds a per-row bf16 table rowtab[pr*384 + n] instead of bias — this is
// W*pos + b, precomputed, so q = out + pos never needs materializing).
// ---------------------------------------------------------------------------
#define LSTR 40   // LDS row stride in shorts (80 B), conflict-light for b128

template<bool RELU, bool F32OUT, bool BF16OUT, bool ROWADD>
__global__ __launch_bounds__(256)
void mfma_gemm(const ushort* __restrict__ A, const ushort* __restrict__ B,
               const float* __restrict__ bias,
               float* __restrict__ Cf, ushort* __restrict__ Cb,
               const ushort* __restrict__ rowtab,
               int N, int K)
{
    __shared__ ushort As[128 * LSTR];
    __shared__ ushort Bs[128 * LSTR];
    const int tid = threadIdx.x;
    const int lane = tid & 63;
    const int wave = tid >> 6;
    const int wr = (wave >> 1) * 64;
    const int wc = (wave & 1) * 64;
    const int rowBase = blockIdx.y * 128;
    const int colBase = blockIdx.x * 128;

    floatx4 acc[4][4];
    #pragma unroll
    for (int i = 0; i < 4; i++)
        #pragma unroll
        for (int j = 0; j < 4; j++) {
            floatx4 z = {0.f, 0.f, 0.f, 0.f};
            acc[i][j] = z;
        }

    const int strow = tid >> 2;
    const int stcol = (tid & 3) * 8;
    const int kq = (lane >> 4) * 8;
    const int lr = lane & 15;

    for (int k0 = 0; k0 < K; k0 += 32) {
        #pragma unroll
        for (int j = 0; j < 2; j++) {
            const int r = j * 64 + strow;
            const uint4 av = *(const uint4*)(A + (size_t)(rowBase + r) * K + k0 + stcol);
            const uint4 bv = *(const uint4*)(B + (size_t)(colBase + r) * K + k0 + stcol);
            *(uint4*)(As + r * LSTR + stcol) = av;
            *(uint4*)(Bs + r * LSTR + stcol) = bv;
        }
        __syncthreads();
        shortx8 af[4], bfr[4];
        #pragma unroll
        for (int t = 0; t < 4; t++) {
            af[t]  = *(const shortx8*)(As + (wr + t * 16 + lr) * LSTR + kq);
            bfr[t] = *(const shortx8*)(Bs + (wc + t * 16 + lr) * LSTR + kq);
        }
        #pragma unroll
        for (int mt = 0; mt < 4; mt++)
            #pragma unroll
            for (int nt = 0; nt < 4; nt++)
                acc[mt][nt] = __builtin_amdgcn_mfma_f32_16x16x32_bf16(
                    af[mt], bfr[nt], acc[mt][nt], 0, 0, 0);
        __syncthreads();
    }

    const int colB = colBase + wc + lr;
    const int rowB = rowBase + wr + (lane >> 4) * 4;
    #pragma unroll
    for (int mt = 0; mt < 4; mt++) {
        #pragma unroll
        for (int r = 0; r < 4; r++) {
            const int m = rowB + mt * 16 + r;
            const int pr = (m >= LQ) ? m - LQ : m;
            #pragma unroll
            for (int nt = 0; nt < 4; nt++) {
                const int n = colB + nt * 16;
                float v = acc[mt][nt][r];
                if (ROWADD) v += b2f(rowtab[(size_t)pr * 384 + n]);
                else        v += bias[n];
                if (RELU) v = fmaxf(v, 0.f);
                if (F32OUT) Cf[(size_t)m * N + n] = v;
                if (BF16OUT) Cb[(size_t)m * N + n] = f2b(v);
            }
        }
    }
}

// ---------------------------------------------------------------------------
// Full-N MFMA GEMM: BM=128, BN=256, BK=32, 512 thr = 8 waves (2 row x 4 col
// quadrants of 64x64). DOUBLE-BUFFERED LDS, ONE barrier per K-step:
//   barrier -> issue loads(k+1) -> ds_read buf[p] + 16 MFMA -> ds_write buf[p^1]
// __launch_bounds__(512, 1): 256-reg cap (round-4's (512,4) forced a 64-VGPR
// cap -> scratch spills -> +80 MB traffic; hipcc's 2nd arg acts CUDA-style,
// blocks/CU).
//
// resid ALWAYS perm-layout float4; PERMC => Cb perm ushort4; LN = fused
// residual+LayerNorm, 16-lane shfl + cross-wave LDS reduce (red aliases As[0]).
// ---------------------------------------------------------------------------
template<bool RELU, bool LN, bool F32OUT, bool BF16OUT, bool PERMC>
__global__ __launch_bounds__(512, 1)
void gemm_fused(const ushort* __restrict__ A, const ushort* __restrict__ B,
                const float* __restrict__ bias,
                float* __restrict__ resid, ushort* __restrict__ Cb,
                const float* __restrict__ g, const float* __restrict__ beta)
{
    __shared__ ushort As[2][128 * LSTR];   // 2 x 10240 B
    __shared__ ushort Bs[2][256 * LSTR];   // 2 x 20480 B

    const int tid = threadIdx.x;
    const int lane = tid & 63;
    const int wave = tid >> 6;            // 0..7
    const int lr = lane & 15;
    const int hi = lane >> 4;
    const int rowBase = blockIdx.x * 128;
    const int wr = (wave >> 2) * 64;      // 0 / 64
    const int wc = (wave & 3) * 64;       // 0,64,128,192

    floatx4 acc[4][4];
    #pragma unroll
    for (int i = 0; i < 4; i++)
        #pragma unroll
        for (int j = 0; j < 4; j++) {
            floatx4 z = {0.f, 0.f, 0.f, 0.f};
            acc[i][j] = z;
        }

    const int strow = tid >> 2;          // 0..127
    const int stcol = (tid & 3) * 8;     // 0,8,16,24 (shorts)
    const int kq = hi * 8;

    const ushort* ag = A + (size_t)(rowBase + strow) * CDIM + stcol;
    const ushort* bg = B + (size_t)strow * CDIM + stcol;

    // prologue: stage tile 0 into buf 0
    {
        const uint4 av  = *(const uint4*)(ag);
        const uint4 bv0 = *(const uint4*)(bg);
        const uint4 bv1 = *(const uint4*)(bg + 128 * CDIM);
        *(uint4*)(As[0] + strow * LSTR + stcol) = av;
        *(uint4*)(Bs[0] + strow * LSTR + stcol) = bv0;
        *(uint4*)(Bs[0] + (strow + 128) * LSTR + stcol) = bv1;
    }

    #pragma unroll
    for (int kt = 0; kt < 8; ++kt) {
        const int p = kt & 1;
        __syncthreads();
        uint4 av, bv0, bv1;
        if (kt < 7) {
            const int ko = (kt + 1) * 32;
            av  = *(const uint4*)(ag + ko);
            bv0 = *(const uint4*)(bg + ko);
            bv1 = *(const uint4*)(bg + ko + 128 * CDIM);
        }
        shortx8 af[4], bfr[4];
        #pragma unroll
        for (int t = 0; t < 4; t++) {
            af[t]  = *(const shortx8*)(As[p] + (wr + t * 16 + lr) * LSTR + kq);
            bfr[t] = *(const shortx8*)(Bs[p] + (wc + t * 16 + lr) * LSTR + kq);
        }
        #pragma unroll
        for (int mt = 0; mt < 4; mt++)
            #pragma unroll
            for (int nt = 0; nt < 4; nt++)
                acc[mt][nt] = __builtin_amdgcn_mfma_f32_16x16x32_bf16(
                    af[mt], bfr[nt], acc[mt][nt], 0, 0, 0);
        if (kt < 7) {
            *(uint4*)(As[p ^ 1] + strow * LSTR + stcol) = av;
            *(uint4*)(Bs[p ^ 1] + strow * LSTR + stcol) = bv0;
            *(uint4*)(Bs[p ^ 1] + (strow + 128) * LSTR + stcol) = bv1;
        }
    }
    __syncthreads();   // K-loop LDS use complete (enables red alias)

    // C/D layout: col = lane&15, row = (lane>>4)*4 + reg  [m89/m91 verified]
    float bcol[4];
    #pragma unroll
    for (int nt = 0; nt < 4; nt++) bcol[nt] = bias[wc + nt * 16 + lr];

    if (LN) {
        float2 (*red)[4] = (float2(*)[4])As[0];   // 128 x 4 x 8 B = 4 KB
        // pass 1: x = acc + bias + resid(perm, float4); per-row partial stats
        #pragma unroll
        for (int mt = 0; mt < 4; mt++) {
            #pragma unroll
            for (int r = 0; r < 4; r++) {
                const int mrel = wr + mt * 16 + hi * 4 + r;
                const int m = rowBase + mrel;
                const float4 rv = *(const float4*)(resid + (size_t)m * CDIM + wc + lr * 4);
                float s = 0.f, sq = 0.f;
                #pragma unroll
                for (int nt = 0; nt < 4; nt++) {
                    float x = acc[mt][nt][r] + bcol[nt] + (&rv.x)[nt];
                    acc[mt][nt][r] = x;
                    s += x; sq += x * x;
                }
                #pragma unroll
                for (int o = 8; o >= 1; o >>= 1) {   // reduce over 16-lane group
                    s  += __shfl_xor(s, o, 64);
                    sq += __shfl_xor(sq, o, 64);
                }
                if (lr == 0) { float2 t2; t2.x = s; t2.y = sq; red[mrel][wave & 3] = t2; }
            }
        }
        __syncthreads();
        float gcol[4], btcol[4];
        #pragma unroll
        for (int nt = 0; nt < 4; nt++) {
            gcol[nt]  = g[wc + nt * 16 + lr];
            btcol[nt] = beta[wc + nt * 16 + lr];
        }
        #pragma unroll
        for (int mt = 0; mt < 4; mt++) {
            #pragma unroll
            for (int r = 0; r < 4; r++) {
                const int mrel = wr + mt * 16 + hi * 4 + r;
                const int m = rowBase + mrel;
                const float2 t0 = red[mrel][0], t1 = red[mrel][1];
                const float2 t2 = red[mrel][2], t3 = red[mrel][3];
                const float S  = (t0.x + t1.x) + (t2.x + t3.x);
                const float SQ = (t0.y + t1.y) + (t2.y + t3.y);
                const float mean = S * (1.0f / CDIM);
                const float var = SQ * (1.0f / CDIM) - mean * mean;
                const float rstd = rsqrtf(var + 1e-5f);
                float4 wv;
                ushort4 ob;
                #pragma unroll
                for (int nt = 0; nt < 4; nt++) {
                    const float y = (acc[mt][nt][r] - mean) * rstd * gcol[nt] + btcol[nt];
                    (&wv.x)[nt] = y;
                    if (BF16OUT) (&ob.x)[nt] = f2b(y);
                }
                *(float4*)(resid + (size_t)m * CDIM + wc + lr * 4) = wv;
                if (BF16OUT) *(ushort4*)(Cb + (size_t)m * CDIM + wc + lr * 4) = ob;
            }
        }
    } else {
        #pragma unroll
        for (int mt = 0; mt < 4; mt++) {
            #pragma unroll
            for (int r = 0; r < 4; r++) {
                const int m = rowBase + wr + mt * 16 + hi * 4 + r;
                float4 wv;
                ushort4 ob;
                #pragma unroll
                for (int nt = 0; nt < 4; nt++) {
                    float y = acc[mt][nt][r] + bcol[nt];
                    if (RELU) y = fmaxf(y, 0.f);
                    (&wv.x)[nt] = y;
                    if (PERMC) {
                        if (BF16OUT) (&ob.x)[nt] = f2b(y);
                    } else {
                        const int col = wc + nt * 16 + lr;
                        if (BF16OUT) Cb[(size_t)m * CDIM + col] = f2b(y);
                    }
                }
                if (F32OUT) *(float4*)(resid + (size_t)m * CDIM + wc + lr * 4) = wv;
                if (PERMC && BF16OUT)
                    *(ushort4*)(Cb + (size_t)m * CDIM + wc + lr * 4) = ob;
            }
        }
    }
}

// ---------------------------------------------------------------------------
// Deformable sampling v2: 2 queries per wave (32 lanes each), lane covers
// 8 channels of one head via uint4 gathers. val/attn in STD layout.
// ---------------------------------------------------------------------------
__global__ __launch_bounds__(256)
void sample_kernel(const ushort* __restrict__ val,
                   const float* __restrict__ offaw,
                   ushort* __restrict__ attn)
{
    const int tid = threadIdx.x;
    const int m = blockIdx.x * 8 + (tid >> 5);   // grid.x = MTOT/8
    const int lane = tid & 31;
    const int head = lane >> 2;                  // 4 lanes per head
    const int c = head * 32 + (lane & 3) * 8;    // 8 channels per lane
    const int b = (m >= LQ) ? 1 : 0;
    const int l = m - (b ? LQ : 0);

    const float* row = offaw + (size_t)m * 128;
    const float4 lg  = *(const float4*)(row + 64 + head * 4);
    const float4 o01 = *(const float4*)(row + head * 8);
    const float4 o23 = *(const float4*)(row + head * 8 + 4);

    const float mx = fmaxf(fmaxf(lg.x, lg.y), fmaxf(lg.z, lg.w));
    const float e0 = expf(lg.x - mx), e1 = expf(lg.y - mx);
    const float e2 = expf(lg.z - mx), e3 = expf(lg.w - mx);
    const float inv = 1.0f / (e0 + e1 + e2 + e3);
    const float awv[4] = {e0 * inv, e1 * inv, e2 * inv, e3 * inv};

    const float lx = (float)(l % WW);
    const float ly = (float)(l / WW);
    const float px[4] = {lx + o01.x, lx + o01.z, lx + o23.x, lx + o23.z};
    const float py[4] = {ly + o01.y, ly + o01.w, ly + o23.y, ly + o23.w};

    const ushort* vb = val + (size_t)b * LQ * CDIM;
    uint4 cv[16];
    float cw[16];
    #pragma unroll
    for (int p = 0; p < POINTS; p++) {
        const float x = px[p], y = py[p];
        const float xf = floorf(x), yf = floorf(y);
        const int x0 = (int)xf, y0 = (int)yf;
        const float wx = x - xf, wy = y - yf;
        const int x0c = min(max(x0, 0), WW - 1);
        const int x1c = min(max(x0 + 1, 0), WW - 1);
        const int y0c = min(max(y0, 0), HH - 1);
        const int y1c = min(max(y0 + 1, 0), HH - 1);
        const float vx0 = (x0 >= 0 && x0 < WW) ? 1.f : 0.f;
        const float vx1 = (x0 + 1 >= 0 && x0 + 1 < WW) ? 1.f : 0.f;
        const float vy0 = (y0 >= 0 && y0 < HH) ? 1.f : 0.f;
        const float vy1 = (y0 + 1 >= 0 && y0 + 1 < HH) ? 1.f : 0.f;
        const float a = awv[p];
        cw[p * 4 + 0] = a * (1.f - wx) * (1.f - wy) * vx0 * vy0;
        cw[p * 4 + 1] = a * wx * (1.f - wy) * vx1 * vy0;
        cw[p * 4 + 2] = a * (1.f - wx) * wy * vx0 * vy1;
        cw[p * 4 + 3] = a * wx * wy * vx1 * vy1;
        const int r0 = y0c * WW, r1 = y1c * WW;
        cv[p * 4 + 0] = *(const uint4*)(vb + (((unsigned)(r0 + x0c)) << 8) + c);
        cv[p * 4 + 1] = *(const uint4*)(vb + (((unsigned)(r0 + x1c)) << 8) + c);
        cv[p * 4 + 2] = *(const uint4*)(vb + (((unsigned)(r1 + x0c)) << 8) + c);
        cv[p * 4 + 3] = *(const uint4*)(vb + (((unsigned)(r1 + x1c)) << 8) + c);
    }
    float a0 = 0.f, a1 = 0.f, a2 = 0.f, a3 = 0.f;
    float a4 = 0.f, a5 = 0.f, a6 = 0.f, a7 = 0.f;
    #pragma unroll
    for (int i = 0; i < 16; i++) {
        const float wgt = cw[i];
        a0 = fmaf(wgt, bitsf(cv[i].x << 16), a0);
        a1 = fmaf(wgt, bitsf(cv[i].x & 0xffff0000u), a1);
        a2 = fmaf(wgt, bitsf(cv[i].y << 16), a2);
        a3 = fmaf(wgt, bitsf(cv[i].y & 0xffff0000u), a3);
        a4 = fmaf(wgt, bitsf(cv[i].z << 16), a4);
        a5 = fmaf(wgt, bitsf(cv[i].z & 0xffff0000u), a5);
        a6 = fmaf(wgt, bitsf(cv[i].w << 16), a6);
        a7 = fmaf(wgt, bitsf(cv[i].w & 0xffff0000u), a7);
    }
    uint4 o;
    o.x = packbf(a0, a1); o.y = packbf(a2, a3);
    o.z = packbf(a4, a5); o.w = packbf(a6, a7);
    *(uint4*)(attn + (size_t)m * CDIM + c) = o;
}

// ---------------------------------------------------------------------------
// Final transpose: [b, l, p] fp32 PERM layout -> d_out [b, c, l] (std).
// ---------------------------------------------------------------------------
__global__ __launch_bounds__(256)
void transpose_out(const float* __restrict__ in, float* __restrict__ outp)
{
    __shared__ float tile[32][33];
    const int b = blockIdx.z;
    const int l0 = blockIdx.x * 32;
    const int c0 = blockIdx.y * 32;
    const float* ib = in + (size_t)b * LQ * CDIM;
    float* ob = outp + (size_t)b * CDIM * LQ;
    #pragma unroll
    for (int j = 0; j < 32; j += 8)
        tile[threadIdx.y + j][threadIdx.x] =
            ib[(size_t)(l0 + threadIdx.y + j) * CDIM + c0 + threadIdx.x];
    __syncthreads();
    #pragma unroll
    for (int j = 0; j < 32; j += 8)
        ob[(size_t)iperm(c0 + threadIdx.y + j) * LQ + l0 + threadIdx.x] =
            tile[threadIdx.x][threadIdx.y + j];
}

// ---------------------------------------------------------------------------
extern "C" void kernel_launch(void* const* d_in, const int* in_sizes, int n_in,
                              void* d_out, int out_size, void* d_ws, size_t ws_size,
                              hipStream_t stream)
{
    const float* bev      = (const float*)d_in[0];
    const float* proj_q_w = (const float*)d_in[1];
    const float* proj_q_b = (const float*)d_in[2];
    const float* off_w    = (const float*)d_in[3];
    const float* off_b    = (const float*)d_in[4];
    const float* aw_w     = (const float*)d_in[5];
    const float* aw_b     = (const float*)d_in[6];
    const float* vp_w     = (const float*)d_in[7];
    const float* vp_b     = (const float*)d_in[8];
    const float* op_w     = (const float*)d_in[9];
    const float* op_b     = (const float*)d_in[10];
    const float* ln1_g    = (const float*)d_in[11];
    const float* ln1_b    = (const float*)d_in[12];
    const float* l1_w     = (const float*)d_in[13];
    const float* l1_b     = (const float*)d_in[14];
    const float* l2_w     = (const float*)d_in[15];
    const float* l2_b     = (const float*)d_in[16];
    const float* ln2_g    = (const float*)d_in[17];
    const float* ln2_b    = (const float*)d_in[18];
    float* outp = (float*)d_out;

    // ---- workspace layout ----
    char* w = (char*)d_ws;
    float*  out_f    = (float*)(w);                    // [MTOT,256] fp32 resid (perm)
    float*  offaw_f  = (float*)(w + 81920000);         // [MTOT,128] fp32 (std)
    ushort* attn_b   = (ushort*)(w + 122880000);       // [MTOT,256] bf16 (std)
    ushort* out_b    = (ushort*)(w + 163840000);       // [MTOT,256] bf16 (perm)
    ushort* posoff_b = (ushort*)(w + 204800000);       // [MPAD,384] bf16 (W*pos+b)
    ushort* val_b    = (ushort*)(w + 245760000);       // [MTOT,256] bf16 (std value; perm hidden)
    ushort* pos_b    = (ushort*)(w + 286720000);       // [LQ,256] bf16 (perm)
    ushort* w_b      = (ushort*)(w + 307200000);       // packed bf16 weights
    ushort* wproj = w_b;                               // 65536 (std k)
    ushort* wvp   = w_b + 65536;                       // 3*65536 (perm k)
    ushort* wop   = w_b + 65536 + 196608;              // (std k)
    ushort* wl1   = w_b + 65536 + 2 * 196608;          // (perm k)
    ushort* wl2   = w_b + 65536 + 3 * 196608;          // (perm k)
    ushort* wofa  = w_b + 65536 + 4 * 196608;          // 3*128*256 = [384][256] (perm k)
    float*  bofa  = (float*)(w + 307200000 + 2 * (65536 + 4 * 196608 + 98304)); // [384]

    const dim3 blk(256);
    const dim3 blk512(512);

    // ---- one-time prep (rerun every call: ws is re-poisoned) ----
    cvt_kernel<<<dim3(65536 / 1024), blk, 0, stream>>>(proj_q_w, wproj);
    cvt_perm_kernel<<<dim3(196608 / 1024), blk, 0, stream>>>(vp_w, wvp);
    cvt_kernel<<<dim3(196608 / 1024), blk, 0, stream>>>(op_w, wop);
    cvt_perm_kernel<<<dim3(196608 / 1024), blk, 0, stream>>>(l1_w, wl1);
    cvt_perm_kernel<<<dim3(196608 / 1024), blk, 0, stream>>>(l2_w, wl2);
    build_offaw<<<dim3(3 * 128), blk, 0, stream>>>(off_w, off_b, aw_w, aw_b, wofa, bofa);
    pos_kernel<<<dim3((LQ * CDIM) / 256), blk, 0, stream>>>(pos_b);
    bevT_kernel<<<dim3(LQ / 32, CDIM / 32, BSZ), dim3(32, 8), 0, stream>>>(bev, val_b);

    // posoff = pos @ [off;aw]^T + b for ALL 3 layers at once: [MPAD, 384] bf16.
    // (M padded to 40064; rows >= LQ read/write garbage, never consumed.)
    mfma_gemm<false, false, true, false><<<dim3(3, MPAD / 128), blk, 0, stream>>>(
        pos_b, wofa, bofa, nullptr, posoff_b, nullptr, 384, CDIM);

    const dim3 gF(MTOT / 128);                 // 625 blocks, BM=128 full-N tiles
    const dim3 g128(1, MTOT / 128);            // per-layer offaw (N=128)

    // proj: out = bevT @ Wq^T + b ; perm resid + perm out_b (no q anymore)
    gemm_fused<false, false, true, true, true><<<gF, blk512, 0, stream>>>(
        val_b, wproj, proj_q_b, out_f, out_b, nullptr, nullptr);

    for (int i = 0; i < NLAYERS; i++) {
        // value = out @ vp^T (std bf16 out for sampler); A perm + k-perm W
        gemm_fused<false, false, false, true, false><<<gF, blk512, 0, stream>>>(
            out_b, wvp + (size_t)i * 65536, vp_b + (size_t)i * CDIM,
            nullptr, val_b, nullptr, nullptr);
        // offaw = out @ W^T + posoff[pr] (fp32 std, N=128); q eliminated
        mfma_gemm<false, true, false, true><<<g128, blk, 0, stream>>>(
            out_b, wofa + (size_t)i * 32768, nullptr,
            offaw_f, nullptr, posoff_b + (size_t)i * 128, 128, CDIM);
        // sampling -> attn (std bf16)
        sample_kernel<<<dim3(MTOT / 8), blk, 0, stream>>>(val_b, offaw_f, attn_b);
        // out = LN(out + attn @ op^T); A std + std W; perm resid + perm out_b
        gemm_fused<false, true, false, true, true><<<gF, blk512, 0, stream>>>(
            attn_b, wop + (size_t)i * 65536, op_b + (size_t)i * CDIM,
            out_f, out_b,
            ln1_g + (size_t)i * CDIM, ln1_b + (size_t)i * CDIM);
        // hidden = relu(out @ l1^T); A perm + k-perm W; perm hidden out
        gemm_fused<true, false, false, true, true><<<gF, blk512, 0, stream>>>(
            out_b, wl1 + (size_t)i * 65536, l1_b + (size_t)i * CDIM,
            nullptr, val_b, nullptr, nullptr);
        // out = LN(out + hidden @ l2^T); A perm + k-perm W; perm resid
        if (i < NLAYERS - 1) {
            gemm_fused<false, true, false, true, true><<<gF, blk512, 0, stream>>>(
                val_b, wl2 + (size_t)i * 65536, l2_b + (size_t)i * CDIM,
                out_f, out_b,
                ln2_g + (size_t)i * CDIM, ln2_b + (size_t)i * CDIM);
        } else {
            gemm_fused<false, true, false, false, true><<<gF, blk512, 0, stream>>>(
                val_b, wl2 + (size_t)i * 65536, l2_b + (size_t)i * CDIM,
                out_f, nullptr,
                ln2_g + (size_t)i * CDIM, ln2_b + (size_t)i * CDIM);
        }
    }

    transpose_out<<<dim3(LQ / 32, CDIM / 32, BSZ), dim3(32, 8), 0, stream>>>(out_f, outp);
}

// Round 7
// 942.580 us; speedup vs baseline: 1.2533x; 1.1077x over previous
//
#include <hip/hip_runtime.h>
#include <math.h>

#define HEADS 8
#define POINTS 4
#define BSZ 2
#define CDIM 256
#define HH 200
#define WW 200
#define LQ (HH * WW)          // 40000
#define MTOT (BSZ * LQ)       // 80000 rows, batch folded into M
#define NLAYERS 3
#define MPAD 40064            // LQ padded to 128 for the posoff GEMM

typedef __attribute__((ext_vector_type(8))) short shortx8;   // 8 bf16 = 4 VGPR
typedef __attribute__((ext_vector_type(4))) float floatx4;

__device__ __forceinline__ ushort f2b(float f) {
    union { float f; unsigned u; } v; v.f = f;
    unsigned r = v.u + 0x7fffu + ((v.u >> 16) & 1u);   // RNE
    return (ushort)(r >> 16);
}
__device__ __forceinline__ float b2f(ushort b) {
    union { unsigned u; float f; } v; v.u = ((unsigned)b) << 16;
    return v.f;
}
__device__ __forceinline__ float bitsf(unsigned u) {
    union { unsigned u; float f; } v; v.u = u;
    return v.f;
}
__device__ __forceinline__ uint packbf(float lo, float hi) {
    return (uint)f2b(lo) | ((uint)f2b(hi) << 16);
}

// Within-64-quadrant channel permutation: channel c = q*64 + nt*16 + lr is
// STORED at position q*64 + lr*4 + nt. Consumers use k-permuted weights so
// GEMM results are unchanged (dot products are order-invariant).
__device__ __forceinline__ int permc(int c) {   // channel -> stored position
    return (c & ~63) | (((c & 15) << 2) | ((c & 63) >> 4));
}
__device__ __forceinline__ int iperm(int p) {   // stored position -> channel
    return (p & ~63) | (((p & 3) << 4) | ((p & 63) >> 2));
}

// ---------------------------------------------------------------------------
// fp32 -> bf16 convert, standard layout (n multiple of 1024)
// ---------------------------------------------------------------------------
__global__ __launch_bounds__(256)
void cvt_kernel(const float* __restrict__ in, ushort* __restrict__ out)
{
    const int i = (blockIdx.x * 256 + threadIdx.x) * 4;
    const float4 v = *(const float4*)(in + i);
    ushort4 o;
    o.x = f2b(v.x); o.y = f2b(v.y); o.z = f2b(v.z); o.w = f2b(v.w);
    *(ushort4*)(out + i) = o;
}

// ---------------------------------------------------------------------------
// fp32 -> bf16 convert with K-PERMUTED columns. out[n][p] = in[n][iperm(p)].
// ---------------------------------------------------------------------------
__global__ __launch_bounds__(256)
void cvt_perm_kernel(const float* __restrict__ in, ushort* __restrict__ out)
{
    const int idx = (blockIdx.x * 256 + threadIdx.x) * 4;   // output position
    const int rowb = idx & ~255;
    const int p0 = idx & 255;
    ushort4 o;
    o.x = f2b(in[rowb + iperm(p0 + 0)]);
    o.y = f2b(in[rowb + iperm(p0 + 1)]);
    o.z = f2b(in[rowb + iperm(p0 + 2)]);
    o.w = f2b(in[rowb + iperm(p0 + 3)]);
    *(ushort4*)(out + idx) = o;
}

// ---------------------------------------------------------------------------
// Build packed off+aw weight [3][128][256] bf16 (K-PERMUTED) + bias fp32.
// ---------------------------------------------------------------------------
__global__ __launch_bounds__(256)
void build_offaw(const float* __restrict__ offw, const float* __restrict__ offb,
                 const float* __restrict__ aww, const float* __restrict__ awb,
                 ushort* __restrict__ wout, float* __restrict__ bout)
{
    const int blk = blockIdx.x;          // 3*128 blocks
    const int i = blk >> 7;
    const int r = blk & 127;
    const int c = threadIdx.x;
    float v = 0.f;
    if (r < 64)      v = offw[((size_t)i * 64 + r) * CDIM + c];
    else if (r < 96) v = aww[((size_t)i * 32 + (r - 64)) * CDIM + c];
    wout[((size_t)i * 128 + r) * CDIM + permc(c)] = f2b(v);
    if (c == 0) {
        float bb = 0.f;
        if (r < 64)      bb = offb[i * 64 + r];
        else if (r < 96) bb = awb[i * 32 + (r - 64)];
        bout[i * 128 + r] = bb;
    }
}

// ---------------------------------------------------------------------------
// Sine positional encoding -> bf16 [LQ, 256], PERM layout
// ---------------------------------------------------------------------------
__global__ __launch_bounds__(256)
void pos_kernel(ushort* __restrict__ pos)
{
    const int idx = blockIdx.x * 256 + threadIdx.x;
    const int c = idx & 255;
    const int l = idx >> 8;
    const int cc = c & 127;
    const float coord = (c < 128) ? (float)(l / WW + 1) : (float)(l % WW + 1);
    const float expo = (float)(2 * (cc >> 1)) * (1.0f / 128.0f);
    const float t = powf(10000.0f, expo);
    const float ph = coord / t;
    pos[(size_t)l * CDIM + permc(c)] = f2b((cc & 1) ? cosf(ph) : sinf(ph));
}

// ---------------------------------------------------------------------------
// bev [BS, C, HW] fp32 -> [BS*HW, C] bf16 STD layout (32x32 LDS transpose)
// ---------------------------------------------------------------------------
__global__ __launch_bounds__(256)
void bevT_kernel(const float* __restrict__ in, ushort* __restrict__ out)
{
    __shared__ float tile[32][33];
    const int b = blockIdx.z;
    const int l0 = blockIdx.x * 32;
    const int c0 = blockIdx.y * 32;
    const float* ib = in + (size_t)b * CDIM * LQ;
    ushort* ob = out + (size_t)b * LQ * CDIM;
    #pragma unroll
    for (int j = 0; j < 32; j += 8)
        tile[threadIdx.y + j][threadIdx.x] =
            ib[(size_t)(c0 + threadIdx.y + j) * LQ + l0 + threadIdx.x];
    __syncthreads();
    #pragma unroll
    for (int j = 0; j < 32; j += 8)
        ob[(size_t)(l0 + threadIdx.y + j) * CDIM + c0 + threadIdx.x] =
            f2b(tile[threadIdx.x][threadIdx.y + j]);
}

// ---------------------------------------------------------------------------
// Legacy 128x128 MFMA GEMM, reg-staged. posoff precompute (N=384, bf16 out)
// and per-layer offaw GEMM (N=128, fp32 out, ROWADD of W*pos+b table).
// ---------------------------------------------------------------------------
#define LSTR 40   // LDS row stride in shorts (80 B)

template<bool RELU, bool F32OUT, bool BF16OUT, bool ROWADD>
__global__ __launch_bounds__(256)
void mfma_gemm(const ushort* __restrict__ A, const ushort* __restrict__ B,
               const float* __restrict__ bias,
               float* __restrict__ Cf, ushort* __restrict__ Cb,
               const ushort* __restrict__ rowtab,
               int N, int K)
{
    __shared__ ushort As[128 * LSTR];
    __shared__ ushort Bs[128 * LSTR];
    const int tid = threadIdx.x;
    const int lane = tid & 63;
    const int wave = tid >> 6;
    const int wr = (wave >> 1) * 64;
    const int wc = (wave & 1) * 64;
    const int rowBase = blockIdx.y * 128;
    const int colBase = blockIdx.x * 128;

    floatx4 acc[4][4];
    #pragma unroll
    for (int i = 0; i < 4; i++)
        #pragma unroll
        for (int j = 0; j < 4; j++) {
            floatx4 z = {0.f, 0.f, 0.f, 0.f};
            acc[i][j] = z;
        }

    const int strow = tid >> 2;
    const int stcol = (tid & 3) * 8;
    const int kq = (lane >> 4) * 8;
    const int lr = lane & 15;

    for (int k0 = 0; k0 < K; k0 += 32) {
        #pragma unroll
        for (int j = 0; j < 2; j++) {
            const int r = j * 64 + strow;
            const uint4 av = *(const uint4*)(A + (size_t)(rowBase + r) * K + k0 + stcol);
            const uint4 bv = *(const uint4*)(B + (size_t)(colBase + r) * K + k0 + stcol);
            *(uint4*)(As + r * LSTR + stcol) = av;
            *(uint4*)(Bs + r * LSTR + stcol) = bv;
        }
        __syncthreads();
        shortx8 af[4], bfr[4];
        #pragma unroll
        for (int t = 0; t < 4; t++) {
            af[t]  = *(const shortx8*)(As + (wr + t * 16 + lr) * LSTR + kq);
            bfr[t] = *(const shortx8*)(Bs + (wc + t * 16 + lr) * LSTR + kq);
        }
        #pragma unroll
        for (int mt = 0; mt < 4; mt++)
            #pragma unroll
            for (int nt = 0; nt < 4; nt++)
                acc[mt][nt] = __builtin_amdgcn_mfma_f32_16x16x32_bf16(
                    af[mt], bfr[nt], acc[mt][nt], 0, 0, 0);
        __syncthreads();
    }

    const int colB = colBase + wc + lr;
    const int rowB = rowBase + wr + (lane >> 4) * 4;
    #pragma unroll
    for (int mt = 0; mt < 4; mt++) {
        #pragma unroll
        for (int r = 0; r < 4; r++) {
            const int m = rowB + mt * 16 + r;
            const int pr = (m >= LQ) ? m - LQ : m;
            #pragma unroll
            for (int nt = 0; nt < 4; nt++) {
                const int n = colB + nt * 16;
                float v = acc[mt][nt][r];
                if (ROWADD) v += b2f(rowtab[(size_t)pr * 384 + n]);
                else        v += bias[n];
                if (RELU) v = fmaxf(v, 0.f);
                if (F32OUT) Cf[(size_t)m * N + n] = v;
                if (BF16OUT) Cb[(size_t)m * N + n] = f2b(v);
            }
        }
    }
}

// ---------------------------------------------------------------------------
// Full-N MFMA GEMM: BM=128, BN=256, BK=32, 512 thr = 8 waves (2x4 of 64x64),
// double-buffered LDS, one barrier per K-step. Used for proj and value GEMMs.
// resid perm-layout float4; PERMC => Cb perm ushort4.
// ---------------------------------------------------------------------------
template<bool RELU, bool F32OUT, bool BF16OUT, bool PERMC>
__global__ __launch_bounds__(512, 1)
void gemm_fused(const ushort* __restrict__ A, const ushort* __restrict__ B,
                const float* __restrict__ bias,
                float* __restrict__ resid, ushort* __restrict__ Cb)
{
    __shared__ ushort As[2][128 * LSTR];   // 2 x 10240 B
    __shared__ ushort Bs[2][256 * LSTR];   // 2 x 20480 B

    const int tid = threadIdx.x;
    const int lane = tid & 63;
    const int wave = tid >> 6;            // 0..7
    const int lr = lane & 15;
    const int hi = lane >> 4;
    const int rowBase = blockIdx.x * 128;
    const int wr = (wave >> 2) * 64;      // 0 / 64
    const int wc = (wave & 3) * 64;       // 0,64,128,192

    floatx4 acc[4][4];
    #pragma unroll
    for (int i = 0; i < 4; i++)
        #pragma unroll
        for (int j = 0; j < 4; j++) {
            floatx4 z = {0.f, 0.f, 0.f, 0.f};
            acc[i][j] = z;
        }

    const int strow = tid >> 2;          // 0..127
    const int stcol = (tid & 3) * 8;     // shorts
    const int kq = hi * 8;

    const ushort* ag = A + (size_t)(rowBase + strow) * CDIM + stcol;
    const ushort* bg = B + (size_t)strow * CDIM + stcol;

    {
        const uint4 av  = *(const uint4*)(ag);
        const uint4 bv0 = *(const uint4*)(bg);
        const uint4 bv1 = *(const uint4*)(bg + 128 * CDIM);
        *(uint4*)(As[0] + strow * LSTR + stcol) = av;
        *(uint4*)(Bs[0] + strow * LSTR + stcol) = bv0;
        *(uint4*)(Bs[0] + (strow + 128) * LSTR + stcol) = bv1;
    }

    #pragma unroll
    for (int kt = 0; kt < 8; ++kt) {
        const int p = kt & 1;
        __syncthreads();
        uint4 av, bv0, bv1;
        if (kt < 7) {
            const int ko = (kt + 1) * 32;
            av  = *(const uint4*)(ag + ko);
            bv0 = *(const uint4*)(bg + ko);
            bv1 = *(const uint4*)(bg + ko + 128 * CDIM);
        }
        shortx8 af[4], bfr[4];
        #pragma unroll
        for (int t = 0; t < 4; t++) {
            af[t]  = *(const shortx8*)(As[p] + (wr + t * 16 + lr) * LSTR + kq);
            bfr[t] = *(const shortx8*)(Bs[p] + (wc + t * 16 + lr) * LSTR + kq);
        }
        #pragma unroll
        for (int mt = 0; mt < 4; mt++)
            #pragma unroll
            for (int nt = 0; nt < 4; nt++)
                acc[mt][nt] = __builtin_amdgcn_mfma_f32_16x16x32_bf16(
                    af[mt], bfr[nt], acc[mt][nt], 0, 0, 0);
        if (kt < 7) {
            *(uint4*)(As[p ^ 1] + strow * LSTR + stcol) = av;
            *(uint4*)(Bs[p ^ 1] + strow * LSTR + stcol) = bv0;
            *(uint4*)(Bs[p ^ 1] + (strow + 128) * LSTR + stcol) = bv1;
        }
    }

    // C/D layout: col = lane&15, row = (lane>>4)*4 + reg  [m89/m91 verified]
    float bcol[4];
    #pragma unroll
    for (int nt = 0; nt < 4; nt++) bcol[nt] = bias[wc + nt * 16 + lr];

    #pragma unroll
    for (int mt = 0; mt < 4; mt++) {
        #pragma unroll
        for (int r = 0; r < 4; r++) {
            const int m = rowBase + wr + mt * 16 + hi * 4 + r;
            float4 wv;
            ushort4 ob;
            #pragma unroll
            for (int nt = 0; nt < 4; nt++) {
                float y = acc[mt][nt][r] + bcol[nt];
                if (RELU) y = fmaxf(y, 0.f);
                (&wv.x)[nt] = y;
                if (PERMC) {
                    if (BF16OUT) (&ob.x)[nt] = f2b(y);
                } else {
                    const int col = wc + nt * 16 + lr;
                    if (BF16OUT) Cb[(size_t)m * CDIM + col] = f2b(y);
                }
            }
            if (F32OUT) *(float4*)(resid + (size_t)m * CDIM + wc + lr * 4) = wv;
            if (PERMC && BF16OUT)
                *(ushort4*)(Cb + (size_t)m * CDIM + wc + lr * 4) = ob;
        }
    }
}

// ---------------------------------------------------------------------------
// FUSED FFN: one kernel per 128 rows computing
//   x1  = resid + attn@Wop^T + op_b           (GEMM1, dbuf staging)
//   y1  = LN1(x1)                             (kept fp32 in acc1; bf16 -> Ls)
//   h   = relu(y1@Wl1^T + l1_b)               (GEMM2: A from Ls, B dbuf; -> Ls)
//   x2  = y1 + h@Wl2^T + l2_b                 (GEMM3: A from Ls, B dbuf)
//   out = LN2(x2)  -> resid (perm fp32) [+ outb perm bf16]
// The LN1 output / hidden tile lives in ONE 68 KB LDS buffer (Ls), written
// in perm col order so Wl1/Wl2 (k-perm) consume it directly. acc1 (fp32 y1)
// stays in registers as the LN2 residual — full fp32 precision, zero traffic.
// LDS: As 20KB + Bs 40KB + Ls 66KB = 126 KB -> 1 block/CU, 8 waves.
// ---------------------------------------------------------------------------
#define LSTR3 264   // Ls row stride in shorts (528 B): 2-way bank alias, free

template<bool BF16OUT>
__global__ __launch_bounds__(512, 1)
void ffn_fused(const ushort* __restrict__ attn, const ushort* __restrict__ Wop,
               const float* __restrict__ opb,
               const ushort* __restrict__ Wl1, const float* __restrict__ l1b,
               const ushort* __restrict__ Wl2, const float* __restrict__ l2b,
               float* __restrict__ resid, ushort* __restrict__ outb,
               const float* __restrict__ g1, const float* __restrict__ b1,
               const float* __restrict__ g2, const float* __restrict__ b2)
{
    __shared__ ushort As[2][128 * LSTR];   // 20480 B (gemm1 A staging / red alias)
    __shared__ ushort Bs[2][256 * LSTR];   // 40960 B (B staging, all 3 GEMMs)
    __shared__ ushort Ls[128 * LSTR3];     // 67584 B (y1 tile, then hidden tile)

    const int tid = threadIdx.x;
    const int lane = tid & 63;
    const int wave = tid >> 6;            // 0..7
    const int lr = lane & 15;
    const int hi = lane >> 4;
    const int rowBase = blockIdx.x * 128;
    const int wr = (wave >> 2) * 64;
    const int wc = (wave & 3) * 64;

    const int strow = tid >> 2;          // 0..127
    const int stcol = (tid & 3) * 8;     // shorts
    const int kq = hi * 8;

    floatx4 acc1[4][4];
    #pragma unroll
    for (int i = 0; i < 4; i++)
        #pragma unroll
        for (int j = 0; j < 4; j++) {
            floatx4 z = {0.f, 0.f, 0.f, 0.f};
            acc1[i][j] = z;
        }

    // ---------------- GEMM1: attn @ Wop^T ----------------
    {
        const ushort* ag = attn + (size_t)(rowBase + strow) * CDIM + stcol;
        const ushort* bg = Wop + (size_t)strow * CDIM + stcol;
        {
            const uint4 av  = *(const uint4*)(ag);
            const uint4 bv0 = *(const uint4*)(bg);
            const uint4 bv1 = *(const uint4*)(bg + 128 * CDIM);
            *(uint4*)(As[0] + strow * LSTR + stcol) = av;
            *(uint4*)(Bs[0] + strow * LSTR + stcol) = bv0;
            *(uint4*)(Bs[0] + (strow + 128) * LSTR + stcol) = bv1;
        }
        #pragma unroll
        for (int kt = 0; kt < 8; ++kt) {
            const int p = kt & 1;
            __syncthreads();
            uint4 av, bv0, bv1;
            if (kt < 7) {
                const int ko = (kt + 1) * 32;
                av  = *(const uint4*)(ag + ko);
                bv0 = *(const uint4*)(bg + ko);
                bv1 = *(const uint4*)(bg + ko + 128 * CDIM);
            }
            shortx8 af[4], bfr[4];
            #pragma unroll
            for (int t = 0; t < 4; t++) {
                af[t]  = *(const shortx8*)(As[p] + (wr + t * 16 + lr) * LSTR + kq);
                bfr[t] = *(const shortx8*)(Bs[p] + (wc + t * 16 + lr) * LSTR + kq);
            }
            #pragma unroll
            for (int mt = 0; mt < 4; mt++)
                #pragma unroll
                for (int nt = 0; nt < 4; nt++)
                    acc1[mt][nt] = __builtin_amdgcn_mfma_f32_16x16x32_bf16(
                        af[mt], bfr[nt], acc1[mt][nt], 0, 0, 0);
            if (kt < 7) {
                *(uint4*)(As[p ^ 1] + strow * LSTR + stcol) = av;
                *(uint4*)(Bs[p ^ 1] + strow * LSTR + stcol) = bv0;
                *(uint4*)(Bs[p ^ 1] + (strow + 128) * LSTR + stcol) = bv1;
            }
        }
        __syncthreads();   // gemm1 LDS use complete
    }

    // ---------------- LN1 (y1 kept in acc1; bf16 copy -> Ls) ----------------
    {
        float bcol[4];
        #pragma unroll
        for (int nt = 0; nt < 4; nt++) bcol[nt] = opb[wc + nt * 16 + lr];
        float2 (*red)[4] = (float2(*)[4])As[0];
        #pragma unroll
        for (int mt = 0; mt < 4; mt++) {
            #pragma unroll
            for (int r = 0; r < 4; r++) {
                const int mrel = wr + mt * 16 + hi * 4 + r;
                const int m = rowBase + mrel;
                const float4 rv = *(const float4*)(resid + (size_t)m * CDIM + wc + lr * 4);
                float s = 0.f, sq = 0.f;
                #pragma unroll
                for (int nt = 0; nt < 4; nt++) {
                    float x = acc1[mt][nt][r] + bcol[nt] + (&rv.x)[nt];
                    acc1[mt][nt][r] = x;
                    s += x; sq += x * x;
                }
                #pragma unroll
                for (int o = 8; o >= 1; o >>= 1) {
                    s  += __shfl_xor(s, o, 64);
                    sq += __shfl_xor(sq, o, 64);
                }
                if (lr == 0) { float2 t2; t2.x = s; t2.y = sq; red[mrel][wave & 3] = t2; }
            }
        }
        __syncthreads();
        float gcol[4], btcol[4];
        #pragma unroll
        for (int nt = 0; nt < 4; nt++) {
            gcol[nt]  = g1[wc + nt * 16 + lr];
            btcol[nt] = b1[wc + nt * 16 + lr];
        }
        #pragma unroll
        for (int mt = 0; mt < 4; mt++) {
            #pragma unroll
            for (int r = 0; r < 4; r++) {
                const int mrel = wr + mt * 16 + hi * 4 + r;
                const float2 t0 = red[mrel][0], t1 = red[mrel][1];
                const float2 t2 = red[mrel][2], t3 = red[mrel][3];
                const float S  = (t0.x + t1.x) + (t2.x + t3.x);
                const float SQ = (t0.y + t1.y) + (t2.y + t3.y);
                const float mean = S * (1.0f / CDIM);
                const float var = SQ * (1.0f / CDIM) - mean * mean;
                const float rstd = rsqrtf(var + 1e-5f);
                ushort4 yb;
                #pragma unroll
                for (int nt = 0; nt < 4; nt++) {
                    const float y = (acc1[mt][nt][r] - mean) * rstd * gcol[nt] + btcol[nt];
                    acc1[mt][nt][r] = y;            // fp32 residual for LN2
                    (&yb.x)[nt] = f2b(y);
                }
                *(ushort4*)(Ls + mrel * LSTR3 + wc + lr * 4) = yb;   // perm cols
            }
        }
    }

    // ---------------- GEMM2: h = relu(y1 @ Wl1^T + l1_b) -> Ls ----------------
    floatx4 acc2[4][4];
    #pragma unroll
    for (int i = 0; i < 4; i++)
        #pragma unroll
        for (int j = 0; j < 4; j++) {
            floatx4 z = {0.f, 0.f, 0.f, 0.f};
            acc2[i][j] = z;
        }
    {
        const ushort* bg = Wl1 + (size_t)strow * CDIM + stcol;
        {
            const uint4 bv0 = *(const uint4*)(bg);
            const uint4 bv1 = *(const uint4*)(bg + 128 * CDIM);
            *(uint4*)(Bs[0] + strow * LSTR + stcol) = bv0;
            *(uint4*)(Bs[0] + (strow + 128) * LSTR + stcol) = bv1;
        }
        #pragma unroll
        for (int kt = 0; kt < 8; ++kt) {
            const int p = kt & 1;
            __syncthreads();           // kt=0: covers Ls(y1) + Bs[0] writes
            uint4 bv0, bv1;
            if (kt < 7) {
                const int ko = (kt + 1) * 32;
                bv0 = *(const uint4*)(bg + ko);
                bv1 = *(const uint4*)(bg + ko + 128 * CDIM);
            }
            shortx8 af[4], bfr[4];
            #pragma unroll
            for (int t = 0; t < 4; t++) {
                af[t]  = *(const shortx8*)(Ls + (wr + t * 16 + lr) * LSTR3 + kt * 32 + kq);
                bfr[t] = *(const shortx8*)(Bs[p] + (wc + t * 16 + lr) * LSTR + kq);
            }
            #pragma unroll
            for (int mt = 0; mt < 4; mt++)
                #pragma unroll
                for (int nt = 0; nt < 4; nt++)
                    acc2[mt][nt] = __builtin_amdgcn_mfma_f32_16x16x32_bf16(
                        af[mt], bfr[nt], acc2[mt][nt], 0, 0, 0);
            if (kt < 7) {
                *(uint4*)(Bs[p ^ 1] + strow * LSTR + stcol) = bv0;
                *(uint4*)(Bs[p ^ 1] + (strow + 128) * LSTR + stcol) = bv1;
            }
        }
        __syncthreads();   // all waves done reading Ls(y1)
        float bcol2[4];
        #pragma unroll
        for (int nt = 0; nt < 4; nt++) bcol2[nt] = l1b[wc + nt * 16 + lr];
        #pragma unroll
        for (int mt = 0; mt < 4; mt++) {
            #pragma unroll
            for (int r = 0; r < 4; r++) {
                const int mrel = wr + mt * 16 + hi * 4 + r;
                ushort4 hb;
                #pragma unroll
                for (int nt = 0; nt < 4; nt++)
                    (&hb.x)[nt] = f2b(fmaxf(acc2[mt][nt][r] + bcol2[nt], 0.f));
                *(ushort4*)(Ls + mrel * LSTR3 + wc + lr * 4) = hb;   // perm cols
            }
        }
    }

    // ---------------- GEMM3: x2 = y1 + h @ Wl2^T + l2_b; LN2 ----------------
    #pragma unroll
    for (int i = 0; i < 4; i++)
        #pragma unroll
        for (int j = 0; j < 4; j++) {
            floatx4 z = {0.f, 0.f, 0.f, 0.f};
            acc2[i][j] = z;
        }
    {
        const ushort* bg = Wl2 + (size_t)strow * CDIM + stcol;
        {
            const uint4 bv0 = *(const uint4*)(bg);
            const uint4 bv1 = *(const uint4*)(bg + 128 * CDIM);
            *(uint4*)(Bs[0] + strow * LSTR + stcol) = bv0;
            *(uint4*)(Bs[0] + (strow + 128) * LSTR + stcol) = bv1;
        }
        #pragma unroll
        for (int kt = 0; kt < 8; ++kt) {
            const int p = kt & 1;
            __syncthreads();           // kt=0: covers Ls(h) + Bs[0] writes
            uint4 bv0, bv1;
            if (kt < 7) {
                const int ko = (kt + 1) * 32;
                bv0 = *(const uint4*)(bg + ko);
                bv1 = *(const uint4*)(bg + ko + 128 * CDIM);
            }
            shortx8 af[4], bfr[4];
            #pragma unroll
            for (int t = 0; t < 4; t++) {
                af[t]  = *(const shortx8*)(Ls + (wr + t * 16 + lr) * LSTR3 + kt * 32 + kq);
                bfr[t] = *(const shortx8*)(Bs[p] + (wc + t * 16 + lr) * LSTR + kq);
            }
            #pragma unroll
            for (int mt = 0; mt < 4; mt++)
                #pragma unroll
                for (int nt = 0; nt < 4; nt++)
                    acc2[mt][nt] = __builtin_amdgcn_mfma_f32_16x16x32_bf16(
                        af[mt], bfr[nt], acc2[mt][nt], 0, 0, 0);
            if (kt < 7) {
                *(uint4*)(Bs[p ^ 1] + strow * LSTR + stcol) = bv0;
                *(uint4*)(Bs[p ^ 1] + (strow + 128) * LSTR + stcol) = bv1;
            }
        }
        __syncthreads();
    }
    {
        float bcol3[4];
        #pragma unroll
        for (int nt = 0; nt < 4; nt++) bcol3[nt] = l2b[wc + nt * 16 + lr];
        float2 (*red)[4] = (float2(*)[4])As[0];
        #pragma unroll
        for (int mt = 0; mt < 4; mt++) {
            #pragma unroll
            for (int r = 0; r < 4; r++) {
                const int mrel = wr + mt * 16 + hi * 4 + r;
                float s = 0.f, sq = 0.f;
                #pragma unroll
                for (int nt = 0; nt < 4; nt++) {
                    float x = acc2[mt][nt][r] + bcol3[nt] + acc1[mt][nt][r];
                    acc2[mt][nt][r] = x;
                    s += x; sq += x * x;
                }
                #pragma unroll
                for (int o = 8; o >= 1; o >>= 1) {
                    s  += __shfl_xor(s, o, 64);
                    sq += __shfl_xor(sq, o, 64);
                }
                if (lr == 0) { float2 t2; t2.x = s; t2.y = sq; red[mrel][wave & 3] = t2; }
            }
        }
        __syncthreads();
        float gcol[4], btcol[4];
        #pragma unroll
        for (int nt = 0; nt < 4; nt++) {
            gcol[nt]  = g2[wc + nt * 16 + lr];
            btcol[nt] = b2[wc + nt * 16 + lr];
        }
        #pragma unroll
        for (int mt = 0; mt < 4; mt++) {
            #pragma unroll
            for (int r = 0; r < 4; r++) {
                const int mrel = wr + mt * 16 + hi * 4 + r;
                const int m = rowBase + mrel;
                const float2 t0 = red[mrel][0], t1 = red[mrel][1];
                const float2 t2 = red[mrel][2], t3 = red[mrel][3];
                const float S  = (t0.x + t1.x) + (t2.x + t3.x);
                const float SQ = (t0.y + t1.y) + (t2.y + t3.y);
                const float mean = S * (1.0f / CDIM);
                const float var = SQ * (1.0f / CDIM) - mean * mean;
                const float rstd = rsqrtf(var + 1e-5f);
                float4 wv;
                ushort4 ob;
                #pragma unroll
                for (int nt = 0; nt < 4; nt++) {
                    const float y = (acc2[mt][nt][r] - mean) * rstd * gcol[nt] + btcol[nt];
                    (&wv.x)[nt] = y;
                    if (BF16OUT) (&ob.x)[nt] = f2b(y);
                }
                *(float4*)(resid + (size_t)m * CDIM + wc + lr * 4) = wv;
                if (BF16OUT) *(ushort4*)(outb + (size_t)m * CDIM + wc + lr * 4) = ob;
            }
        }
    }
}

// ---------------------------------------------------------------------------
// Deformable sampling v2: 2 queries per wave (32 lanes each), lane covers
// 8 channels of one head via uint4 gathers. val/attn in STD layout.
// ---------------------------------------------------------------------------
__global__ __launch_bounds__(256)
void sample_kernel(const ushort* __restrict__ val,
                   const float* __restrict__ offaw,
                   ushort* __restrict__ attn)
{
    const int tid = threadIdx.x;
    const int m = blockIdx.x * 8 + (tid >> 5);   // grid.x = MTOT/8
    const int lane = tid & 31;
    const int head = lane >> 2;                  // 4 lanes per head
    const int c = head * 32 + (lane & 3) * 8;    // 8 channels per lane
    const int b = (m >= LQ) ? 1 : 0;
    const int l = m - (b ? LQ : 0);

    const float* row = offaw + (size_t)m * 128;
    const float4 lg  = *(const float4*)(row + 64 + head * 4);
    const float4 o01 = *(const float4*)(row + head * 8);
    const float4 o23 = *(const float4*)(row + head * 8 + 4);

    const float mx = fmaxf(fmaxf(lg.x, lg.y), fmaxf(lg.z, lg.w));
    const float e0 = expf(lg.x - mx), e1 = expf(lg.y - mx);
    const float e2 = expf(lg.z - mx), e3 = expf(lg.w - mx);
    const float inv = 1.0f / (e0 + e1 + e2 + e3);
    const float awv[4] = {e0 * inv, e1 * inv, e2 * inv, e3 * inv};

    const float lx = (float)(l % WW);
    const float ly = (float)(l / WW);
    const float px[4] = {lx + o01.x, lx + o01.z, lx + o23.x, lx + o23.z};
    const float py[4] = {ly + o01.y, ly + o01.w, ly + o23.y, ly + o23.w};

    const ushort* vb = val + (size_t)b * LQ * CDIM;
    uint4 cv[16];
    float cw[16];
    #pragma unroll
    for (int p = 0; p < POINTS; p++) {
        const float x = px[p], y = py[p];
        const float xf = floorf(x), yf = floorf(y);
        const int x0 = (int)xf, y0 = (int)yf;
        const float wx = x - xf, wy = y - yf;
        const int x0c = min(max(x0, 0), WW - 1);
        const int x1c = min(max(x0 + 1, 0), WW - 1);
        const int y0c = min(max(y0, 0), HH - 1);
        const int y1c = min(max(y0 + 1, 0), HH - 1);
        const float vx0 = (x0 >= 0 && x0 < WW) ? 1.f : 0.f;
        const float vx1 = (x0 + 1 >= 0 && x0 + 1 < WW) ? 1.f : 0.f;
        const float vy0 = (y0 >= 0 && y0 < HH) ? 1.f : 0.f;
        const float vy1 = (y0 + 1 >= 0 && y0 + 1 < HH) ? 1.f : 0.f;
        const float a = awv[p];
        cw[p * 4 + 0] = a * (1.f - wx) * (1.f - wy) * vx0 * vy0;
        cw[p * 4 + 1] = a * wx * (1.f - wy) * vx1 * vy0;
        cw[p * 4 + 2] = a * (1.f - wx) * wy * vx0 * vy1;
        cw[p * 4 + 3] = a * wx * wy * vx1 * vy1;
        const int r0 = y0c * WW, r1 = y1c * WW;
        cv[p * 4 + 0] = *(const uint4*)(vb + (((unsigned)(r0 + x0c)) << 8) + c);
        cv[p * 4 + 1] = *(const uint4*)(vb + (((unsigned)(r0 + x1c)) << 8) + c);
        cv[p * 4 + 2] = *(const uint4*)(vb + (((unsigned)(r1 + x0c)) << 8) + c);
        cv[p * 4 + 3] = *(const uint4*)(vb + (((unsigned)(r1 + x1c)) << 8) + c);
    }
    float a0 = 0.f, a1 = 0.f, a2 = 0.f, a3 = 0.f;
    float a4 = 0.f, a5 = 0.f, a6 = 0.f, a7 = 0.f;
    #pragma unroll
    for (int i = 0; i < 16; i++) {
        const float wgt = cw[i];
        a0 = fmaf(wgt, bitsf(cv[i].x << 16), a0);
        a1 = fmaf(wgt, bitsf(cv[i].x & 0xffff0000u), a1);
        a2 = fmaf(wgt, bitsf(cv[i].y << 16), a2);
        a3 = fmaf(wgt, bitsf(cv[i].y & 0xffff0000u), a3);
        a4 = fmaf(wgt, bitsf(cv[i].z << 16), a4);
        a5 = fmaf(wgt, bitsf(cv[i].z & 0xffff0000u), a5);
        a6 = fmaf(wgt, bitsf(cv[i].w << 16), a6);
        a7 = fmaf(wgt, bitsf(cv[i].w & 0xffff0000u), a7);
    }
    uint4 o;
    o.x = packbf(a0, a1); o.y = packbf(a2, a3);
    o.z = packbf(a4, a5); o.w = packbf(a6, a7);
    *(uint4*)(attn + (size_t)m * CDIM + c) = o;
}

// ---------------------------------------------------------------------------
// Final transpose: [b, l, p] fp32 PERM layout -> d_out [b, c, l] (std).
// ---------------------------------------------------------------------------
__global__ __launch_bounds__(256)
void transpose_out(const float* __restrict__ in, float* __restrict__ outp)
{
    __shared__ float tile[32][33];
    const int b = blockIdx.z;
    const int l0 = blockIdx.x * 32;
    const int c0 = blockIdx.y * 32;
    const float* ib = in + (size_t)b * LQ * CDIM;
    float* ob = outp + (size_t)b * CDIM * LQ;
    #pragma unroll
    for (int j = 0; j < 32; j += 8)
        tile[threadIdx.y + j][threadIdx.x] =
            ib[(size_t)(l0 + threadIdx.y + j) * CDIM + c0 + threadIdx.x];
    __syncthreads();
    #pragma unroll
    for (int j = 0; j < 32; j += 8)
        ob[(size_t)iperm(c0 + threadIdx.y + j) * LQ + l0 + threadIdx.x] =
            tile[threadIdx.x][threadIdx.y + j];
}

// ---------------------------------------------------------------------------
extern "C" void kernel_launch(void* const* d_in, const int* in_sizes, int n_in,
                              void* d_out, int out_size, void* d_ws, size_t ws_size,
                              hipStream_t stream)
{
    const float* bev      = (const float*)d_in[0];
    const float* proj_q_w = (const float*)d_in[1];
    const float* proj_q_b = (const float*)d_in[2];
    const float* off_w    = (const float*)d_in[3];
    const float* off_b    = (const float*)d_in[4];
    const float* aw_w     = (const float*)d_in[5];
    const float* aw_b     = (const float*)d_in[6];
    const float* vp_w     = (const float*)d_in[7];
    const float* vp_b     = (const float*)d_in[8];
    const float* op_w     = (const float*)d_in[9];
    const float* op_b     = (const float*)d_in[10];
    const float* ln1_g    = (const float*)d_in[11];
    const float* ln1_b    = (const float*)d_in[12];
    const float* l1_w     = (const float*)d_in[13];
    const float* l1_b     = (const float*)d_in[14];
    const float* l2_w     = (const float*)d_in[15];
    const float* l2_b     = (const float*)d_in[16];
    const float* ln2_g    = (const float*)d_in[17];
    const float* ln2_b    = (const float*)d_in[18];
    float* outp = (float*)d_out;

    // ---- workspace layout ----
    char* w = (char*)d_ws;
    float*  out_f    = (float*)(w);                    // [MTOT,256] fp32 resid (perm)
    float*  offaw_f  = (float*)(w + 81920000);         // [MTOT,128] fp32 (std)
    ushort* attn_b   = (ushort*)(w + 122880000);       // [MTOT,256] bf16 (std)
    ushort* out_b    = (ushort*)(w + 163840000);       // [MTOT,256] bf16 (perm)
    ushort* posoff_b = (ushort*)(w + 204800000);       // [MPAD,384] bf16 (W*pos+b)
    ushort* val_b    = (ushort*)(w + 245760000);       // [MTOT,256] bf16 (std value)
    ushort* pos_b    = (ushort*)(w + 286720000);       // [LQ,256] bf16 (perm)
    ushort* w_b      = (ushort*)(w + 307200000);       // packed bf16 weights
    ushort* wproj = w_b;                               // 65536 (std k)
    ushort* wvp   = w_b + 65536;                       // 3*65536 (perm k)
    ushort* wop   = w_b + 65536 + 196608;              // (std k)
    ushort* wl1   = w_b + 65536 + 2 * 196608;          // (perm k)
    ushort* wl2   = w_b + 65536 + 3 * 196608;          // (perm k)
    ushort* wofa  = w_b + 65536 + 4 * 196608;          // 3*128*256 = [384][256] (perm k)
    float*  bofa  = (float*)(w + 307200000 + 2 * (65536 + 4 * 196608 + 98304)); // [384]

    const dim3 blk(256);
    const dim3 blk512(512);

    // ---- one-time prep (rerun every call: ws is re-poisoned) ----
    cvt_kernel<<<dim3(65536 / 1024), blk, 0, stream>>>(proj_q_w, wproj);
    cvt_perm_kernel<<<dim3(196608 / 1024), blk, 0, stream>>>(vp_w, wvp);
    cvt_kernel<<<dim3(196608 / 1024), blk, 0, stream>>>(op_w, wop);
    cvt_perm_kernel<<<dim3(196608 / 1024), blk, 0, stream>>>(l1_w, wl1);
    cvt_perm_kernel<<<dim3(196608 / 1024), blk, 0, stream>>>(l2_w, wl2);
    build_offaw<<<dim3(3 * 128), blk, 0, stream>>>(off_w, off_b, aw_w, aw_b, wofa, bofa);
    pos_kernel<<<dim3((LQ * CDIM) / 256), blk, 0, stream>>>(pos_b);
    bevT_kernel<<<dim3(LQ / 32, CDIM / 32, BSZ), dim3(32, 8), 0, stream>>>(bev, val_b);

    // posoff = pos @ [off;aw]^T + b for ALL 3 layers: [MPAD, 384] bf16.
    mfma_gemm<false, false, true, false><<<dim3(3, MPAD / 128), blk, 0, stream>>>(
        pos_b, wofa, bofa, nullptr, posoff_b, nullptr, 384, CDIM);

    const dim3 gF(MTOT / 128);                 // 625 blocks, BM=128 full-N tiles
    const dim3 g128(1, MTOT / 128);            // per-layer offaw (N=128)

    // proj: out = bevT @ Wq^T + b ; perm resid + perm out_b
    gemm_fused<false, true, true, true><<<gF, blk512, 0, stream>>>(
        val_b, wproj, proj_q_b, out_f, out_b);

    for (int i = 0; i < NLAYERS; i++) {
        // value = out @ vp^T (std bf16 out for sampler); A perm + k-perm W
        gemm_fused<false, false, true, false><<<gF, blk512, 0, stream>>>(
            out_b, wvp + (size_t)i * 65536, vp_b + (size_t)i * CDIM,
            nullptr, val_b);
        // offaw = out @ W^T + posoff[pr] (fp32 std, N=128)
        mfma_gemm<false, true, false, true><<<g128, blk, 0, stream>>>(
            out_b, wofa + (size_t)i * 32768, nullptr,
            offaw_f, nullptr, posoff_b + (size_t)i * 128, 128, CDIM);
        // sampling -> attn (std bf16)
        sample_kernel<<<dim3(MTOT / 8), blk, 0, stream>>>(val_b, offaw_f, attn_b);
        // FUSED: out = LN2(LN1(out + attn@op) + relu(LN1out@l1)@l2)
        if (i < NLAYERS - 1) {
            ffn_fused<true><<<gF, blk512, 0, stream>>>(
                attn_b, wop + (size_t)i * 65536, op_b + (size_t)i * CDIM,
                wl1 + (size_t)i * 65536, l1_b + (size_t)i * CDIM,
                wl2 + (size_t)i * 65536, l2_b + (size_t)i * CDIM,
                out_f, out_b,
                ln1_g + (size_t)i * CDIM, ln1_b + (size_t)i * CDIM,
                ln2_g + (size_t)i * CDIM, ln2_b + (size_t)i * CDIM);
        } else {
            ffn_fused<false><<<gF, blk512, 0, stream>>>(
                attn_b, wop + (size_t)i * 65536, op_b + (size_t)i * CDIM,
                wl1 + (size_t)i * 65536, l1_b + (size_t)i * CDIM,
                wl2 + (size_t)i * 65536, l2_b + (size_t)i * CDIM,
                out_f, nullptr,
                ln1_g + (size_t)i * CDIM, ln1_b + (size_t)i * CDIM,
                ln2_g + (size_t)i * CDIM, ln2_b + (size_t)i * CDIM);
        }
    }

    transpose_out<<<dim3(LQ / 32, CDIM / 32, BSZ), dim3(32, 8), 0, stream>>>(out_f, outp);
}